// Round 13
// baseline (365.183 us; speedup 1.0000x reference)
//
#include <hip/hip_runtime.h>
#include <hip/hip_bf16.h>
#include <cstdint>
#include <cstddef>

typedef __bf16 bf16;
typedef bf16 bf16x4 __attribute__((ext_vector_type(4)));
typedef bf16 bf16x8 __attribute__((ext_vector_type(8)));
typedef float floatx4 __attribute__((ext_vector_type(4)));
typedef float floatx16 __attribute__((ext_vector_type(16)));
typedef unsigned int uint;

#define MFMA16(a, b, c) __builtin_amdgcn_mfma_f32_16x16x32_bf16((a), (b), (c), 0, 0, 0)
#define MFMA32(a, b, c) __builtin_amdgcn_mfma_f32_32x32x16_bf16((a), (b), (c), 0, 0, 0)

// log2(e)/8: S is the RAW k.q dot; softmax uses exp(S/8) = exp2(S*K2)
#define K2 0.18033688011112042f

__device__ __forceinline__ void async16(const void* g, void* l) {
    __builtin_amdgcn_global_load_lds((const __attribute__((address_space(1))) void*)g,
                                     (__attribute__((address_space(3))) void*)l,
                                     16, 0, 0);
}

// swizzled tile stage: each wave stages 16 rows (2 async16). wave in 0..3 -> 64
// rows; wave in 0..7 -> 128 rows.
__device__ __forceinline__ void stage64s(const bf16* g0, int ldg, bf16* lds, int wave, int lane) {
#pragma unroll
    for (int i = 0; i < 2; ++i) {
        int r0 = wave * 16 + i * 8;  // wave-uniform
        async16(g0 + (size_t)(r0 + (lane >> 3)) * ldg + ((lane & 7) ^ (lane >> 3)) * 8,
                lds + r0 * 64);
    }
}
// 8-wave stage of a 64-row tile: each wave stages 8 rows (1 async16).
__device__ __forceinline__ void stage64q(const bf16* g0, int ldg, bf16* lds, int wave, int lane) {
    int r0 = wave * 8;  // wave-uniform
    async16(g0 + (size_t)(r0 + (lane >> 3)) * ldg + ((lane & 7) ^ (lane >> 3)) * 8,
            lds + r0 * 64);
}
// R13: K-row-permuted stage — LDS row j holds GLOBAL row pi(j), pi = swap
// bits 2,3 of j. With A = pi-staged K, the S' = MFMA(K,Q) output lands in
// registers already in the PV A-fragment layout for BOTH lane halves (the
// contraction over c is permutation-invariant, so P and V stay consistent:
// V's k-dim reads natural c order, which is exactly what permuted P now
// provides). Kills the 8 ds_bpermute (__shfl_xor 32) per iter.
// LDS dest stays wave-uniform linear; only the per-lane GLOBAL row changes.
// Column swizzle keys on the LDS row bits (lane>>3 = j&7) -> self-consistent.
__device__ __forceinline__ void stage64p(const bf16* g0, int ldg, bf16* lds, int wave, int lane) {
    int j = wave * 8 + (lane >> 3);
    int pj = (j & ~12) | ((j & 4) << 1) | ((j & 8) >> 1);
    async16(g0 + (size_t)pj * ldg + ((lane & 7) ^ (lane >> 3)) * 8,
            lds + wave * 8 * 64);
}
__device__ __forceinline__ bf16x8 rd64(const bf16* t, int row, int chunk) {
    return *(const bf16x8*)&t[row * 64 + ((chunk ^ (row & 7)) * 8)];
}
// R12: chunk XOR uses (row>>1)&3 — 2-way (free) instead of 4-way conflicts.
__device__ __forceinline__ bf16x8 rd32(const bf16* t, int row, int quad) {
    return *(const bf16x8*)&t[row * 32 + ((quad ^ ((row >> 1) & 3)) * 8)];
}

// pack two f32 -> one u32 of 2 bf16
__device__ __forceinline__ uint pk2(float lo, float hi) {
    union { bf16 h[2]; uint u; } c;
    c.h[0] = (bf16)lo;
    c.h[1] = (bf16)hi;
    return c.u;
}

// ---------------------------------------------------------------------------
// Fused fp32->bf16 convert
// ---------------------------------------------------------------------------
__global__ __launch_bounds__(256) void cvt_all(const float* __restrict__ x,
                                               const float* __restrict__ WQ,
                                               const float* __restrict__ WK,
                                               const float* __restrict__ WV,
                                               const float* __restrict__ WO,
                                               const float* __restrict__ Win,
                                               const float* __restrict__ Wout,
                                               bf16* __restrict__ xb,
                                               bf16* __restrict__ wqkv,
                                               bf16* __restrict__ wo,
                                               bf16* __restrict__ win,
                                               bf16* __restrict__ wout) {
    int blk = blockIdx.x;
    const float* src;
    bf16* dst;
    int off;
    if (blk < 1024)      { src = WQ;   dst = wqkv;           off = blk; }
    else if (blk < 2048) { src = WK;   dst = wqkv + 1048576; off = blk - 1024; }
    else if (blk < 3072) { src = WV;   dst = wqkv + 2097152; off = blk - 2048; }
    else if (blk < 4096) { src = WO;   dst = wo;             off = blk - 3072; }
    else if (blk < 8192) { src = Win;  dst = win;            off = blk - 4096; }
    else if (blk < 12288){ src = Wout; dst = wout;           off = blk - 8192; }
    else                 { src = x;    dst = xb;             off = blk - 12288; }
    int i = off * 1024 + threadIdx.x * 4;
    float4 v = *(const float4*)(src + i);
    bf16x4 o = {(bf16)v.x, (bf16)v.y, (bf16)v.z, (bf16)v.w};
    *(bf16x4*)(dst + i) = o;
}

// ---------------------------------------------------------------------------
// Epilogue shared by the GEMM templates.
// ---------------------------------------------------------------------------
template <int EPI, int NACC>
__device__ __forceinline__ void epilogue(floatx4 (&acc)[4][NACC], int m0, int n0,
                                         int wm, int wn, int col, int quad,
                                         float* Cf, bf16* Cb, int ldc,
                                         const float* bias, const float* res) {
#pragma unroll
    for (int mi = 0; mi < 4; ++mi)
#pragma unroll
        for (int ni = 0; ni < NACC; ++ni)
#pragma unroll
            for (int r = 0; r < 4; ++r) {
                int row = m0 + wm + mi * 16 + quad * 4 + r;
                int cc = n0 + wn + ni * 16 + col;
                size_t idx = (size_t)row * ldc + cc;
                float v = acc[mi][ni][r];
                if constexpr (EPI == 0) {
                    Cb[idx] = (bf16)v;
                } else if constexpr (EPI == 1) {
                    v += res[idx];
                    Cf[idx] = v;
                    Cb[idx] = (bf16)v;
                } else if constexpr (EPI == 2) {
                    v += bias[cc];
                    v = fmaxf(v, 0.f);
                    Cb[idx] = (bf16)v;
                } else {
                    v += bias[cc] + Cf[idx];
                    Cf[idx] = v;
                }
            }
}

// ---------------------------------------------------------------------------
// gemm_pipe: 128x128 tile, BK=32, 3-stage LDS pipeline, fine vmcnt.
// ---------------------------------------------------------------------------
template <int EPI>
__global__ __launch_bounds__(256) void gemm_pipe(const bf16* __restrict__ A, int lda,
                                                 const bf16* __restrict__ B, int ldb, int K,
                                                 float* __restrict__ Cf, bf16* __restrict__ Cb,
                                                 int ldc, const float* __restrict__ bias,
                                                 const float* __restrict__ res) {
    __shared__ __align__(16) bf16 As[3][128 * 32];
    __shared__ __align__(16) bf16 Bs[3][128 * 32];
    const int tid = threadIdx.x, wave = tid >> 6, lane = tid & 63;
    const int m0 = blockIdx.y * 128, n0 = blockIdx.x * 128;
    const int wm = (wave >> 1) * 64, wn = (wave & 1) * 64;
    const int col = lane & 15, quad = lane >> 4;
    const int cs8 = ((lane & 3) ^ ((lane >> 3) & 3)) * 8;

    floatx4 acc[4][4];
#pragma unroll
    for (int mi = 0; mi < 4; ++mi)
#pragma unroll
        for (int ni = 0; ni < 4; ++ni) acc[mi][ni] = (floatx4){0.f, 0.f, 0.f, 0.f};

    auto stage = [&](int buf, int k0) {
#pragma unroll
        for (int i = 0; i < 2; ++i) {
            int r0 = wave * 32 + i * 16;
            async16(A + (size_t)(m0 + r0 + (lane >> 2)) * lda + k0 + cs8,
                    As[buf] + r0 * 32);
            async16(B + (size_t)(n0 + r0 + (lane >> 2)) * ldb + k0 + cs8,
                    Bs[buf] + r0 * 32);
        }
    };

    const int nk = K / 32;
    stage(0, 0);
    stage(1, 32);
    for (int it = 0; it < nk; ++it) {
        if (it + 1 < nk) asm volatile("s_waitcnt vmcnt(4)" ::: "memory");
        else             asm volatile("s_waitcnt vmcnt(0)" ::: "memory");
        __builtin_amdgcn_s_barrier();
        if (it + 2 < nk) stage((it + 2) % 3, (it + 2) * 32);

        const bf16* as = As[it % 3];
        const bf16* bs = Bs[it % 3];
        bf16x8 af[4], bfr[4];
#pragma unroll
        for (int mi = 0; mi < 4; ++mi) af[mi] = rd32(as, wm + mi * 16 + col, quad);
#pragma unroll
        for (int ni = 0; ni < 4; ++ni) bfr[ni] = rd32(bs, wn + ni * 16 + col, quad);
#pragma unroll
        for (int mi = 0; mi < 4; ++mi)
#pragma unroll
            for (int ni = 0; ni < 4; ++ni)
                acc[mi][ni] = MFMA16(af[mi], bfr[ni], acc[mi][ni]);
    }
    epilogue<EPI, 4>(acc, m0, n0, wm, wn, col, quad, Cf, Cb, ldc, bias, res);
}

// ---------------------------------------------------------------------------
// gemm_deep: 256x256 tile, 8 waves (512 thr), BK=64 in two 32-wide k-halves,
// LDS 128 KB (1 block/CU), 4 phases per K-tile, counted per-half vmcnt.
// Optional split-K via blockIdx.z.
// ---------------------------------------------------------------------------
template <int EPI>
__global__ __launch_bounds__(512, 2) void gemm_deep(const bf16* __restrict__ A, int lda,
                                                    const bf16* __restrict__ B, int ldb, int K,
                                                    bf16* __restrict__ Cb, int ldc,
                                                    const float* __restrict__ bias) {
    __shared__ __align__(16) bf16 As[2][2][256 * 32];
    __shared__ __align__(16) bf16 Bs[2][2][256 * 32];
    const int tid = threadIdx.x, wave = tid >> 6, lane = tid & 63;
    const int gx = gridDim.x;
    const int orig = blockIdx.y * gx + blockIdx.x;
    const int cpx = (gx * gridDim.y) >> 3;
    const int swz = (orig & 7) * cpx + (orig >> 3);
    const int m0 = (swz % gx) * 256, n0 = (swz / gx) * 256;
    // split-K offsets (no-op when gridDim.z == 1)
    A += (size_t)blockIdx.z * K;
    B += (size_t)blockIdx.z * K;
    Cb += (size_t)blockIdx.z * (size_t)gx * 256 * ldc;
    const int wm = (wave >> 2) * 128, wn = (wave & 3) * 64;
    const int col = lane & 15, quad = lane >> 4;
    const int cs8 = ((lane & 3) ^ ((lane >> 3) & 3)) * 8;

    floatx4 acc[8][4];
#pragma unroll
    for (int mi = 0; mi < 8; ++mi)
#pragma unroll
        for (int ni = 0; ni < 4; ++ni) acc[mi][ni] = (floatx4){0.f, 0.f, 0.f, 0.f};

    auto stA = [&](int buf, int kh, int kb) {
#pragma unroll
        for (int i = 0; i < 2; ++i) {
            int r0 = wave * 32 + i * 16;
            async16(A + (size_t)(m0 + r0 + (lane >> 2)) * lda + kb + kh * 32 + cs8,
                    As[buf][kh] + r0 * 32);
        }
    };
    auto stB = [&](int buf, int kh, int kb) {
#pragma unroll
        for (int i = 0; i < 2; ++i) {
            int r0 = wave * 32 + i * 16;
            async16(B + (size_t)(n0 + r0 + (lane >> 2)) * ldb + kb + kh * 32 + cs8,
                    Bs[buf][kh] + r0 * 32);
        }
    };

    const int nk = K / 64;
    stA(0, 0, 0); stB(0, 0, 0); stA(0, 1, 0); stB(0, 1, 0);
    asm volatile("s_waitcnt vmcnt(4)" ::: "memory");
    __builtin_amdgcn_s_barrier();

    for (int t = 0; t < nk; ++t) {
        const int c = t & 1, nb = c ^ 1;
        const bf16* a0 = As[c][0];
        const bf16* a1 = As[c][1];
        const bf16* b0s = Bs[c][0];
        const bf16* b1s = Bs[c][1];
        const int kb1 = (t + 1) * 64;
        const bool pre = (t + 1 < nk);
        bf16x8 bfr[4], af[4];

        // ---- p0: (k0, mh0) ----
        if (pre) stA(nb, 0, kb1);
#pragma unroll
        for (int ni = 0; ni < 4; ++ni) bfr[ni] = rd32(b0s, wn + ni * 16 + col, quad);
#pragma unroll
        for (int mi = 0; mi < 4; ++mi) af[mi] = rd32(a0, wm + mi * 16 + col, quad);
        __builtin_amdgcn_s_barrier();
        asm volatile("s_waitcnt lgkmcnt(0)" ::: "memory");
        __builtin_amdgcn_s_setprio(1);
#pragma unroll
        for (int mi = 0; mi < 4; ++mi)
#pragma unroll
            for (int ni = 0; ni < 4; ++ni)
                acc[mi][ni] = MFMA16(af[mi], bfr[ni], acc[mi][ni]);
        __builtin_amdgcn_s_setprio(0);
        __builtin_amdgcn_s_barrier();

        // ---- p1: (k0, mh1) ----
        if (pre) stB(nb, 0, kb1);
#pragma unroll
        for (int mi = 0; mi < 4; ++mi) af[mi] = rd32(a0, wm + 64 + mi * 16 + col, quad);
        __builtin_amdgcn_s_barrier();
        asm volatile("s_waitcnt lgkmcnt(0)" ::: "memory");
        __builtin_amdgcn_s_setprio(1);
#pragma unroll
        for (int mi = 0; mi < 4; ++mi)
#pragma unroll
            for (int ni = 0; ni < 4; ++ni)
                acc[mi + 4][ni] = MFMA16(af[mi], bfr[ni], acc[mi + 4][ni]);
        __builtin_amdgcn_s_setprio(0);
        if (pre) asm volatile("s_waitcnt vmcnt(4)" ::: "memory");
        else     asm volatile("s_waitcnt vmcnt(0)" ::: "memory");
        __builtin_amdgcn_s_barrier();

        // ---- p2: (k1, mh0) ----
        if (pre) stA(nb, 1, kb1);
#pragma unroll
        for (int ni = 0; ni < 4; ++ni) bfr[ni] = rd32(b1s, wn + ni * 16 + col, quad);
#pragma unroll
        for (int mi = 0; mi < 4; ++mi) af[mi] = rd32(a1, wm + mi * 16 + col, quad);
        __builtin_amdgcn_s_barrier();
        asm volatile("s_waitcnt lgkmcnt(0)" ::: "memory");
        __builtin_amdgcn_s_setprio(1);
#pragma unroll
        for (int mi = 0; mi < 4; ++mi)
#pragma unroll
            for (int ni = 0; ni < 4; ++ni)
                acc[mi][ni] = MFMA16(af[mi], bfr[ni], acc[mi][ni]);
        __builtin_amdgcn_s_setprio(0);
        __builtin_amdgcn_s_barrier();

        // ---- p3: (k1, mh1) ----
        if (pre) stB(nb, 1, kb1);
#pragma unroll
        for (int mi = 0; mi < 4; ++mi) af[mi] = rd32(a1, wm + 64 + mi * 16 + col, quad);
        __builtin_amdgcn_s_barrier();
        asm volatile("s_waitcnt lgkmcnt(0)" ::: "memory");
        __builtin_amdgcn_s_setprio(1);
#pragma unroll
        for (int mi = 0; mi < 4; ++mi)
#pragma unroll
            for (int ni = 0; ni < 4; ++ni)
                acc[mi + 4][ni] = MFMA16(af[mi], bfr[ni], acc[mi + 4][ni]);
        __builtin_amdgcn_s_setprio(0);
        if (pre) asm volatile("s_waitcnt vmcnt(4)" ::: "memory");
        else     asm volatile("s_waitcnt vmcnt(0)" ::: "memory");
        __builtin_amdgcn_s_barrier();
    }

#pragma unroll
    for (int mi = 0; mi < 8; ++mi)
#pragma unroll
        for (int ni = 0; ni < 4; ++ni)
#pragma unroll
            for (int r = 0; r < 4; ++r) {
                int row = m0 + wm + mi * 16 + quad * 4 + r;
                int cc = n0 + wn + ni * 16 + col;
                size_t idx = (size_t)row * ldc + cc;
                float v = acc[mi][ni][r];
                if constexpr (EPI == 2) {
                    v += bias[cc];
                    v = fmaxf(v, 0.f);
                    Cb[idx] = (bf16)v;
                } else {
                    Cb[idx] = (bf16)v;
                }
            }
}

// ---------------------------------------------------------------------------
// mlp2_reduce: out += p0+p1+p2+p3 + bout  (bf16 partials).
// ---------------------------------------------------------------------------
__global__ __launch_bounds__(256) void mlp2_reduce(const bf16* __restrict__ p,
                                                   const float* __restrict__ bout,
                                                   float* __restrict__ out) {
    int i = (blockIdx.x * 256 + threadIdx.x) * 4;
    float4 o = *(const float4*)(out + i);
    float4 bb = *(const float4*)(bout + (i & 1023));
    float s0 = 0.f, s1 = 0.f, s2 = 0.f, s3 = 0.f;
#pragma unroll
    for (int z = 0; z < 4; ++z) {
        bf16x4 v = *(const bf16x4*)(p + (size_t)z * 4194304 + i);
        s0 += (float)v[0];
        s1 += (float)v[1];
        s2 += (float)v[2];
        s3 += (float)v[3];
    }
    o.x += s0 + bb.x;
    o.y += s1 + bb.y;
    o.z += s2 + bb.z;
    o.w += s3 + bb.w;
    *(float4*)(out + i) = o;
}

// ---------------------------------------------------------------------------
// gemm_pipe64: 128x64 tile, BK=64, 3-stage pipeline, counted vmcnt(6),
// XCD-chunked. rd64-family swizzle (conflict-free). Used for WO.
// ---------------------------------------------------------------------------
template <int EPI>
__global__ __launch_bounds__(256) void gemm_pipe64(const bf16* __restrict__ A, int lda,
                                                   const bf16* __restrict__ B, int ldb, int K,
                                                   float* __restrict__ Cf, bf16* __restrict__ Cb,
                                                   int ldc, const float* __restrict__ bias,
                                                   const float* __restrict__ res) {
    __shared__ __align__(16) bf16 As[3][128 * 64];
    __shared__ __align__(16) bf16 Bs[3][64 * 64];
    const int tid = threadIdx.x, wave = tid >> 6, lane = tid & 63;
    const int orig = blockIdx.y * 16 + blockIdx.x;
    const int wgid = (orig & 7) * 64 + (orig >> 3);
    const int m0 = (wgid >> 4) * 128, n0 = (wgid & 15) * 64;
    const int wm = (wave >> 1) * 64, wn = (wave & 1) * 32;
    const int col = lane & 15, quad = lane >> 4;
    const int rsub = lane >> 3;
    const int csub = ((lane & 7) ^ rsub) * 8;

    floatx4 acc[4][2];
#pragma unroll
    for (int mi = 0; mi < 4; ++mi)
#pragma unroll
        for (int ni = 0; ni < 2; ++ni) acc[mi][ni] = (floatx4){0.f, 0.f, 0.f, 0.f};

    auto stage = [&](int buf, int k0) {
#pragma unroll
        for (int i = 0; i < 4; ++i) {
            int r0 = wave * 32 + i * 8;
            async16(A + (size_t)(m0 + r0 + rsub) * lda + k0 + csub, As[buf] + r0 * 64);
        }
#pragma unroll
        for (int i = 0; i < 2; ++i) {
            int r0 = wave * 16 + i * 8;
            async16(B + (size_t)(n0 + r0 + rsub) * ldb + k0 + csub, Bs[buf] + r0 * 64);
        }
    };

    const int nk = K / 64;
    stage(0, 0);
    stage(1, 64);
    for (int it = 0; it < nk; ++it) {
        if (it + 1 < nk) asm volatile("s_waitcnt vmcnt(6)" ::: "memory");
        else             asm volatile("s_waitcnt vmcnt(0)" ::: "memory");
        __builtin_amdgcn_s_barrier();
        if (it + 2 < nk) stage((it + 2) % 3, (it + 2) * 64);

        const bf16* as = As[it % 3];
        const bf16* bs = Bs[it % 3];
#pragma unroll
        for (int ks = 0; ks < 2; ++ks) {
            bf16x8 af[4], bfr[2];
#pragma unroll
            for (int mi = 0; mi < 4; ++mi) {
                int row = wm + mi * 16 + col;
                af[mi] = *(const bf16x8*)&as[row * 64 + (((ks * 4 + quad) ^ (row & 7)) * 8)];
            }
#pragma unroll
            for (int ni = 0; ni < 2; ++ni) {
                int row = wn + ni * 16 + col;
                bfr[ni] = *(const bf16x8*)&bs[row * 64 + (((ks * 4 + quad) ^ (row & 7)) * 8)];
            }
#pragma unroll
            for (int mi = 0; mi < 4; ++mi)
#pragma unroll
                for (int ni = 0; ni < 2; ++ni)
                    acc[mi][ni] = MFMA16(af[mi], bfr[ni], acc[mi][ni]);
        }
    }
    epilogue<EPI, 2>(acc, m0, n0, wm, wn, col, quad, Cf, Cb, ldc, bias, res);
}

// ---------------------------------------------------------------------------
// Transpose V, folding in the softmax denominator: vt[h][c] = V[c][h] / l_c.
// ---------------------------------------------------------------------------
__global__ __launch_bounds__(256) void transpose_v(const bf16* __restrict__ qkv,
                                                   const float* __restrict__ linv,
                                                   bf16* __restrict__ vt) {
    __shared__ bf16 t[64][65];
    const int bh = blockIdx.y, ct = blockIdx.x;
    const int b = bh >> 4, a = bh & 15;
    const float* lv = linv + (size_t)bh * 2048 + ct * 64;
    for (int idx = threadIdx.x; idx < 4096; idx += 256) {
        int c = idx >> 6, h = idx & 63;
        float v = (float)qkv[(size_t)(b * 2048 + ct * 64 + c) * 3072 + 2048 + a * 64 + h];
        t[h][c] = (bf16)(v * lv[c]);
    }
    __syncthreads();
    for (int idx = threadIdx.x; idx < 4096; idx += 256) {
        int h = idx >> 6, c = idx & 63;
        vt[(size_t)(bh * 64 + h) * 2048 + ct * 64 + c] = t[h][c];
    }
}

// ---------------------------------------------------------------------------
// Attention pass 1: 128 c-rows per block, 8 waves (512 thr).
// l_c = sum_{C<=c} exp(S/8); stores linv[c] = 1/l_c.
// ---------------------------------------------------------------------------
__global__ __launch_bounds__(512, 4) void attn_stats(const bf16* __restrict__ qkv,
                                                     float* __restrict__ linv) {
    __shared__ __align__(16) bf16 Kt[128 * 64];   // 16 KB
    __shared__ __align__(16) bf16 Qt[3][64 * 64]; // 24 KB
    __shared__ float red[4][32];                  // cross-qh combine
    const int xx = blockIdx.x;
    const int t = (xx & 1) ? (15 - (xx >> 1)) : (xx >> 1);
    const int bh = blockIdx.y;
    const int b = bh >> 4, a = bh & 15;
    const int tid = threadIdx.x, wave = tid >> 6, lane = tid & 63;
    const int l31 = lane & 31, lh = lane >> 5;
    const int kq = wave & 3, qh = wave >> 2;
    const bf16* base = qkv + (size_t)b * 2048 * 3072;
    const int c0 = t * 128;
    const int niter = 2 * t + 2;

    stage64s(base + (size_t)c0 * 3072 + 1024 + a * 64, 3072, Kt, wave, lane);
    stage64q(base + a * 64, 3072, Qt[0], wave, lane);
    stage64q(base + (size_t)64 * 3072 + a * 64, 3072, Qt[1], wave, lane);

    float lrun[16];
#pragma unroll
    for (int r = 0; r < 16; ++r) lrun[r] = 0.f;
    bf16x8 kf[4];

    for (int i = 0; i < niter; ++i) {
        if (i + 1 < niter) asm volatile("s_waitcnt vmcnt(1)" ::: "memory");
        else               asm volatile("s_waitcnt vmcnt(0)" ::: "memory");
        __builtin_amdgcn_s_barrier();
        if (i + 2 < niter)
            stage64q(base + (size_t)(i + 2) * 64 * 3072 + a * 64, 3072,
                     Qt[(i + 2) % 3], wave, lane);
        if (i == 0) {
#pragma unroll
            for (int s = 0; s < 4; ++s) kf[s] = rd64(Kt, 32 * kq + l31, 2 * s + lh);
        }
        const bf16* q = Qt[i % 3];
        bf16x8 qf0 = rd64(q, 32 * qh + l31, 0 + lh);
        bf16x8 qf1 = rd64(q, 32 * qh + l31, 2 + lh);
        bf16x8 qf2 = rd64(q, 32 * qh + l31, 4 + lh);
        bf16x8 qf3 = rd64(q, 32 * qh + l31, 6 + lh);
        floatx16 s0 = (floatx16)0.f, s1 = (floatx16)0.f;
        __builtin_amdgcn_s_setprio(1);
        s0 = MFMA32(kf[0], qf0, s0);
        s1 = MFMA32(kf[2], qf2, s1);
        s0 = MFMA32(kf[1], qf1, s0);
        s1 = MFMA32(kf[3], qf3, s1);
        __builtin_amdgcn_s_setprio(0);
#pragma unroll
        for (int r = 0; r < 16; ++r) {
            float e = __builtin_amdgcn_exp2f((s0[r] + s1[r]) * K2);
            if (i >= niter - 2) {
                int Crel = 64 * (i - 2 * t) + 32 * qh + l31;
                int crel = 32 * kq + (r & 3) + 8 * (r >> 2) + 4 * lh;
                if (Crel > crel) e = 0.f;
            }
            lrun[r] += e;
        }
    }
#pragma unroll
    for (int r = 0; r < 16; ++r) {
        float v = lrun[r];
        v += __shfl_xor(v, 1);
        v += __shfl_xor(v, 2);
        v += __shfl_xor(v, 4);
        v += __shfl_xor(v, 8);
        v += __shfl_xor(v, 16);
        lrun[r] = v;
    }
    if (qh == 1 && l31 == 0) {
#pragma unroll
        for (int r = 0; r < 16; ++r)
            red[kq][(r & 3) + 8 * (r >> 2) + 4 * lh] = lrun[r];
    }
    __syncthreads();
    if (qh == 0 && l31 == 0) {
#pragma unroll
        for (int r = 0; r < 16; ++r) {
            int cr = (r & 3) + 8 * (r >> 2) + 4 * lh;
            linv[(size_t)bh * 2048 + c0 + 32 * kq + cr] = 1.0f / (lrun[r] + red[kq][cr]);
        }
    }
}

// ---------------------------------------------------------------------------
// Attention pass 2 (R13): 128 C-rows per block, 8 waves (512 thr).
// z[C][h] = sum_{c>=C} exp2(S[c][C]*K2) * V'[c][h]  (V' = V/l_c prefolded).
// K rows staged with pi (swap bits 2,3) -> S' output registers ARE the PV
// A-fragments: no cross-lane exchange, no per-half select. Causal mask uses
// pi-adjusted crel. V/Q staging and all else unchanged from R12.
// ---------------------------------------------------------------------------
__global__ __launch_bounds__(512, 4) void attn_av(const bf16* __restrict__ qkv,
                                                  const bf16* __restrict__ vt,
                                                  bf16* __restrict__ zb) {
    __shared__ __align__(16) char smem[65536];
    bf16* Qt = (bf16*)smem;             // 16 KB, 128 rows
    bf16* Kt = (bf16*)(smem + 16384);   // 3 x 8 KB
    bf16* Vt = (bf16*)(smem + 40960);   // 3 x 8 KB
    const int xx = blockIdx.x;
    const int t = (xx & 1) ? (15 - (xx >> 1)) : (xx >> 1);
    const int bh = blockIdx.y;
    const int b = bh >> 4, a = bh & 15;
    const int tid = threadIdx.x, wave = tid >> 6, lane = tid & 63;
    const int l31 = lane & 31, lh = lane >> 5;
    const int Cq = wave & 3, cq = wave >> 2;
    const bf16* base = qkv + (size_t)b * 2048 * 3072;
    const int C0 = t * 128;
    const int niter = 32 - 2 * t;

    stage64s(base + (size_t)C0 * 3072 + a * 64, 3072, Qt, wave, lane);  // 128 Q rows
    stage64p(base + (size_t)(2 * t) * 64 * 3072 + 1024 + a * 64, 3072, Kt, wave, lane);
    stage64q(vt + (size_t)bh * 64 * 2048 + 2 * t * 64, 2048, Vt, wave, lane);
    stage64p(base + (size_t)(2 * t + 1) * 64 * 3072 + 1024 + a * 64, 3072, Kt + 4096, wave, lane);
    stage64q(vt + (size_t)bh * 64 * 2048 + (2 * t + 1) * 64, 2048, Vt + 4096, wave, lane);

    floatx16 zacc[2];
    zacc[0] = (floatx16)0.f;
    zacc[1] = (floatx16)0.f;
    bf16x8 qf[4];

    for (int i = 0; i < niter; ++i) {
        const int ct = 2 * t + i;
        if (i + 1 < niter) asm volatile("s_waitcnt vmcnt(2)" ::: "memory");
        else               asm volatile("s_waitcnt vmcnt(0)" ::: "memory");
        __builtin_amdgcn_s_barrier();
        if (i + 2 < niter) {
            stage64p(base + (size_t)(ct + 2) * 64 * 3072 + 1024 + a * 64, 3072,
                     Kt + ((i + 2) % 3) * 4096, wave, lane);
            stage64q(vt + (size_t)bh * 64 * 2048 + (ct + 2) * 64, 2048,
                     Vt + ((i + 2) % 3) * 4096, wave, lane);
        }
        if (i == 0) {
#pragma unroll
            for (int s = 0; s < 4; ++s) qf[s] = rd64(Qt, 32 * Cq + l31, 2 * s + lh);
        }
        const bf16* kt = Kt + (i % 3) * 4096;
        const bf16* vts = Vt + (i % 3) * 4096;

        // S'[pi-row, C] quadrant: A = permuted K rows (32cq + l31), B = Q rows
        floatx16 s0 = (floatx16)0.f, s1 = (floatx16)0.f;
        __builtin_amdgcn_s_setprio(1);
        s0 = MFMA32(rd64(kt, 32 * cq + l31, 0 + lh), qf[0], s0);
        s1 = MFMA32(rd64(kt, 32 * cq + l31, 4 + lh), qf[2], s1);
        s0 = MFMA32(rd64(kt, 32 * cq + l31, 2 + lh), qf[1], s0);
        s1 = MFMA32(rd64(kt, 32 * cq + l31, 6 + lh), qf[3], s1);
        __builtin_amdgcn_s_setprio(0);

        // reg r holds c = 64*i + 32*cq + pi(c_off); pi-adjusted:
        // crel = (r&3) + ((r>>2)&1)*4 + lh*8 + (r>>3)*16
        float p[16];
#pragma unroll
        for (int r = 0; r < 16; ++r) {
            float e = __builtin_amdgcn_exp2f((s0[r] + s1[r]) * K2);
            if (i < 2) {
                int Crel = 32 * Cq + l31;
                int crel = 64 * i + 32 * cq + (r & 3) + (((r >> 2) & 1) << 2) +
                           (lh << 3) + (((r >> 3) & 1) << 4);
                if (Crel > crel) e = 0.f;
            }
            p[r] = e;
        }

        // Permuted S' registers are ALREADY the PV A-fragments: direct pack.
        bf16x8 pa[2];
#pragma unroll
        for (int g = 0; g < 2; ++g) {
            union { uint u[4]; bf16x8 v; } cv;
            cv.u[0] = pk2(p[8 * g + 0], p[8 * g + 1]);
            cv.u[1] = pk2(p[8 * g + 2], p[8 * g + 3]);
            cv.u[2] = pk2(p[8 * g + 4], p[8 * g + 5]);
            cv.u[3] = pk2(p[8 * g + 6], p[8 * g + 7]);
            pa[g] = cv.v;
        }

        // z[C, h] += P'[C, c] * V'[c, h]
        __builtin_amdgcn_s_setprio(1);
#pragma unroll
        for (int ht = 0; ht < 2; ++ht) {
#pragma unroll
            for (int s = 0; s < 2; ++s) {
                bf16x8 vf = rd64(vts, 32 * ht + l31, 4 * cq + 2 * s + lh);
                zacc[ht] = MFMA32(pa[s], vf, zacc[ht]);
            }
        }
        __builtin_amdgcn_s_setprio(0);
    }

    __syncthreads();
    float* Zex = (float*)smem;
    if (cq == 1) {
#pragma unroll
        for (int ht = 0; ht < 2; ++ht)
#pragma unroll
            for (int q = 0; q < 4; ++q) {
                float4 t4 = {zacc[ht][4 * q + 0], zacc[ht][4 * q + 1],
                             zacc[ht][4 * q + 2], zacc[ht][4 * q + 3]};
                *(float4*)&Zex[Cq * 2048 + lane * 32 + (((ht * 4 + q) ^ (lane & 7)) * 4)] = t4;
            }
    }
    __syncthreads();
    if (cq == 0) {
#pragma unroll
        for (int ht = 0; ht < 2; ++ht)
#pragma unroll
            for (int q = 0; q < 4; ++q) {
                float4 t4 = *(const float4*)&Zex[Cq * 2048 + lane * 32 +
                                                 (((ht * 4 + q) ^ (lane & 7)) * 4)];
                zacc[ht][4 * q + 0] += t4.x;
                zacc[ht][4 * q + 1] += t4.y;
                zacc[ht][4 * q + 2] += t4.z;
                zacc[ht][4 * q + 3] += t4.w;
            }
#pragma unroll
        for (int ht = 0; ht < 2; ++ht)
#pragma unroll
            for (int r = 0; r < 16; ++r) {
                int Cg = C0 + 32 * Cq + (r & 3) + 8 * (r >> 2) + 4 * lh;
                zb[(size_t)(b * 2048 + Cg) * 1024 + a * 64 + 32 * ht + l31] =
                    (bf16)zacc[ht][r];
            }
    }
}

// ---------------------------------------------------------------------------
// Host launcher
// ---------------------------------------------------------------------------
extern "C" void kernel_launch(void* const* d_in, const int* in_sizes, int n_in,
                              void* d_out, int out_size, void* d_ws, size_t ws_size,
                              hipStream_t stream) {
    (void)in_sizes; (void)n_in; (void)out_size; (void)ws_size;
    const float* x    = (const float*)d_in[0];
    const float* WK   = (const float*)d_in[1];
    const float* WQ   = (const float*)d_in[2];
    const float* WV   = (const float*)d_in[3];
    const float* WO   = (const float*)d_in[4];
    const float* Win  = (const float*)d_in[5];
    const float* bin  = (const float*)d_in[6];
    const float* Wout = (const float*)d_in[7];
    const float* bout = (const float*)d_in[8];
    float* out = (float*)d_out;

    char* ws = (char*)d_ws;
    bf16*  xb   = (bf16*)(ws + 0);          //  8 MB
    bf16*  wqkv = (bf16*)(ws + 8388608);    //  6 MB
    bf16*  wo   = (bf16*)(ws + 14680064);   //  2 MB
    bf16*  win  = (bf16*)(ws + 16777216);   //  8 MB
    bf16*  wout = (bf16*)(ws + 25165824);   //  8 MB
    bf16*  qkvb = (bf16*)(ws + 33554432);   // 24 MB (dead after attn)
    bf16*  vtb  = (bf16*)(ws + 58720256);   //  8 MB (dead after attn)
    float* mst  = (float*)(ws + 67108864);  // 256 KB (linv)
    bf16*  zbuf = (bf16*)(ws + 67633152);   //  8 MB
    bf16*  xmid = (bf16*)(ws + 76021760);   //  8 MB
    bf16*  hbuf = (bf16*)(ws + 84410368);   // 32 MB
    bf16*  partb = (bf16*)(ws + 33554432);  // 32 MB = 4 x 8 MB bf16 partials
                                            // (aliases qkvb+vtb, dead by MLP2)

    cvt_all<<<16384, 256, 0, stream>>>(x, WQ, WK, WV, WO, Win, Wout,
                                       xb, wqkv, wo, win, wout);

    // QKV: [4096x1024] x [3072x1024]^T (3 blocks/CU -> pipe)
    gemm_pipe<0><<<dim3(24, 32), 256, 0, stream>>>(xb, 1024, wqkv, 1024, 1024,
                                                   nullptr, qkvb, 3072, nullptr, nullptr);
    attn_stats<<<dim3(16, 32), 512, 0, stream>>>(qkvb, mst);
    transpose_v<<<dim3(32, 32), 256, 0, stream>>>(qkvb, mst, vtb);
    attn_av<<<dim3(16, 32), 512, 0, stream>>>(qkvb, vtb, zbuf);
    // WO: z @ W_O^T + x (pipelined BK=64, XCD-chunked)
    gemm_pipe64<1><<<dim3(16, 32), 256, 0, stream>>>(zbuf, 1024, wo, 1024, 1024,
                                                     out, xmid, 1024, nullptr, x);
    // MLP1: relu(xmid @ W_in^T + b_in) — 256^2 4-phase deep-pipe, 1 block/CU
    gemm_deep<2><<<dim3(16, 16), 512, 0, stream>>>(xmid, 1024, win, 1024, 1024,
                                                   hbuf, 4096, bin);
    // MLP2: 256^2 4-phase deep-pipe, split-K=4 (256 blocks = 1/CU), bf16
    // partials into dead attn buffers, then fused reduce (+b_out).
    gemm_deep<0><<<dim3(16, 4, 4), 512, 0, stream>>>(hbuf, 4096, wout, 4096, 1024,
                                                     partb, 1024, nullptr);
    mlp2_reduce<<<4096, 256, 0, stream>>>(partb, bout, out);
}

// Round 14
// 360.844 us; speedup vs baseline: 1.0120x; 1.0120x over previous
//
#include <hip/hip_runtime.h>
#include <hip/hip_bf16.h>
#include <cstdint>
#include <cstddef>

typedef __bf16 bf16;
typedef bf16 bf16x4 __attribute__((ext_vector_type(4)));
typedef bf16 bf16x8 __attribute__((ext_vector_type(8)));
typedef float floatx4 __attribute__((ext_vector_type(4)));
typedef float floatx16 __attribute__((ext_vector_type(16)));
typedef unsigned int uint;

#define MFMA16(a, b, c) __builtin_amdgcn_mfma_f32_16x16x32_bf16((a), (b), (c), 0, 0, 0)
#define MFMA32(a, b, c) __builtin_amdgcn_mfma_f32_32x32x16_bf16((a), (b), (c), 0, 0, 0)

// log2(e)/8: S is the RAW k.q dot; softmax uses exp(S/8) = exp2(S*K2)
#define K2 0.18033688011112042f

__device__ __forceinline__ void async16(const void* g, void* l) {
    __builtin_amdgcn_global_load_lds((const __attribute__((address_space(1))) void*)g,
                                     (__attribute__((address_space(3))) void*)l,
                                     16, 0, 0);
}

// swizzled tile stage: each wave stages 16 rows (2 async16). wave in 0..3 -> 64
// rows; wave in 0..7 -> 128 rows.
__device__ __forceinline__ void stage64s(const bf16* g0, int ldg, bf16* lds, int wave, int lane) {
#pragma unroll
    for (int i = 0; i < 2; ++i) {
        int r0 = wave * 16 + i * 8;  // wave-uniform
        async16(g0 + (size_t)(r0 + (lane >> 3)) * ldg + ((lane & 7) ^ (lane >> 3)) * 8,
                lds + r0 * 64);
    }
}
// 8-wave stage of a 64-row tile: each wave stages 8 rows (1 async16).
__device__ __forceinline__ void stage64q(const bf16* g0, int ldg, bf16* lds, int wave, int lane) {
    int r0 = wave * 8;  // wave-uniform
    async16(g0 + (size_t)(r0 + (lane >> 3)) * ldg + ((lane & 7) ^ (lane >> 3)) * 8,
            lds + r0 * 64);
}
// R13: K-row-permuted stage — LDS row j holds GLOBAL row pi(j), pi = swap
// bits 2,3 of j. S' = MFMA(piK, Q) lands registers directly in the PV
// A-fragment layout (contraction over c is permutation-invariant).
__device__ __forceinline__ void stage64p(const bf16* g0, int ldg, bf16* lds, int wave, int lane) {
    int j = wave * 8 + (lane >> 3);
    int pj = (j & ~12) | ((j & 4) << 1) | ((j & 8) >> 1);
    async16(g0 + (size_t)pj * ldg + ((lane & 7) ^ (lane >> 3)) * 8,
            lds + wave * 8 * 64);
}
__device__ __forceinline__ bf16x8 rd64(const bf16* t, int row, int chunk) {
    return *(const bf16x8*)&t[row * 64 + ((chunk ^ (row & 7)) * 8)];
}
// R12: chunk XOR uses (row>>1)&3 — 2-way (free) instead of 4-way conflicts.
__device__ __forceinline__ bf16x8 rd32(const bf16* t, int row, int quad) {
    return *(const bf16x8*)&t[row * 32 + ((quad ^ ((row >> 1) & 3)) * 8)];
}

// pack two f32 -> one u32 of 2 bf16
__device__ __forceinline__ uint pk2(float lo, float hi) {
    union { bf16 h[2]; uint u; } c;
    c.h[0] = (bf16)lo;
    c.h[1] = (bf16)hi;
    return c.u;
}

// ---------------------------------------------------------------------------
// Fused fp32->bf16 convert
// ---------------------------------------------------------------------------
__global__ __launch_bounds__(256) void cvt_all(const float* __restrict__ x,
                                               const float* __restrict__ WQ,
                                               const float* __restrict__ WK,
                                               const float* __restrict__ WV,
                                               const float* __restrict__ WO,
                                               const float* __restrict__ Win,
                                               const float* __restrict__ Wout,
                                               bf16* __restrict__ xb,
                                               bf16* __restrict__ wqkv,
                                               bf16* __restrict__ wo,
                                               bf16* __restrict__ win,
                                               bf16* __restrict__ wout) {
    int blk = blockIdx.x;
    const float* src;
    bf16* dst;
    int off;
    if (blk < 1024)      { src = WQ;   dst = wqkv;           off = blk; }
    else if (blk < 2048) { src = WK;   dst = wqkv + 1048576; off = blk - 1024; }
    else if (blk < 3072) { src = WV;   dst = wqkv + 2097152; off = blk - 2048; }
    else if (blk < 4096) { src = WO;   dst = wo;             off = blk - 3072; }
    else if (blk < 8192) { src = Win;  dst = win;            off = blk - 4096; }
    else if (blk < 12288){ src = Wout; dst = wout;           off = blk - 8192; }
    else                 { src = x;    dst = xb;             off = blk - 12288; }
    int i = off * 1024 + threadIdx.x * 4;
    float4 v = *(const float4*)(src + i);
    bf16x4 o = {(bf16)v.x, (bf16)v.y, (bf16)v.z, (bf16)v.w};
    *(bf16x4*)(dst + i) = o;
}

// ---------------------------------------------------------------------------
// Epilogue shared by the GEMM templates.
// ---------------------------------------------------------------------------
template <int EPI, int NACC>
__device__ __forceinline__ void epilogue(floatx4 (&acc)[4][NACC], int m0, int n0,
                                         int wm, int wn, int col, int quad,
                                         float* Cf, bf16* Cb, int ldc,
                                         const float* bias, const float* res) {
#pragma unroll
    for (int mi = 0; mi < 4; ++mi)
#pragma unroll
        for (int ni = 0; ni < NACC; ++ni)
#pragma unroll
            for (int r = 0; r < 4; ++r) {
                int row = m0 + wm + mi * 16 + quad * 4 + r;
                int cc = n0 + wn + ni * 16 + col;
                size_t idx = (size_t)row * ldc + cc;
                float v = acc[mi][ni][r];
                if constexpr (EPI == 0) {
                    Cb[idx] = (bf16)v;
                } else if constexpr (EPI == 1) {
                    v += res[idx];
                    Cf[idx] = v;
                    Cb[idx] = (bf16)v;
                } else if constexpr (EPI == 2) {
                    v += bias[cc];
                    v = fmaxf(v, 0.f);
                    Cb[idx] = (bf16)v;
                } else {
                    v += bias[cc] + Cf[idx];
                    Cf[idx] = v;
                }
            }
}

// ---------------------------------------------------------------------------
// gemm_pipe: 128x128 tile, BK=32, 3-stage LDS pipeline, fine vmcnt.
// ---------------------------------------------------------------------------
template <int EPI>
__global__ __launch_bounds__(256) void gemm_pipe(const bf16* __restrict__ A, int lda,
                                                 const bf16* __restrict__ B, int ldb, int K,
                                                 float* __restrict__ Cf, bf16* __restrict__ Cb,
                                                 int ldc, const float* __restrict__ bias,
                                                 const float* __restrict__ res) {
    __shared__ __align__(16) bf16 As[3][128 * 32];
    __shared__ __align__(16) bf16 Bs[3][128 * 32];
    const int tid = threadIdx.x, wave = tid >> 6, lane = tid & 63;
    const int m0 = blockIdx.y * 128, n0 = blockIdx.x * 128;
    const int wm = (wave >> 1) * 64, wn = (wave & 1) * 64;
    const int col = lane & 15, quad = lane >> 4;
    const int cs8 = ((lane & 3) ^ ((lane >> 3) & 3)) * 8;

    floatx4 acc[4][4];
#pragma unroll
    for (int mi = 0; mi < 4; ++mi)
#pragma unroll
        for (int ni = 0; ni < 4; ++ni) acc[mi][ni] = (floatx4){0.f, 0.f, 0.f, 0.f};

    auto stage = [&](int buf, int k0) {
#pragma unroll
        for (int i = 0; i < 2; ++i) {
            int r0 = wave * 32 + i * 16;
            async16(A + (size_t)(m0 + r0 + (lane >> 2)) * lda + k0 + cs8,
                    As[buf] + r0 * 32);
            async16(B + (size_t)(n0 + r0 + (lane >> 2)) * ldb + k0 + cs8,
                    Bs[buf] + r0 * 32);
        }
    };

    const int nk = K / 32;
    stage(0, 0);
    stage(1, 32);
    for (int it = 0; it < nk; ++it) {
        if (it + 1 < nk) asm volatile("s_waitcnt vmcnt(4)" ::: "memory");
        else             asm volatile("s_waitcnt vmcnt(0)" ::: "memory");
        __builtin_amdgcn_s_barrier();
        if (it + 2 < nk) stage((it + 2) % 3, (it + 2) * 32);

        const bf16* as = As[it % 3];
        const bf16* bs = Bs[it % 3];
        bf16x8 af[4], bfr[4];
#pragma unroll
        for (int mi = 0; mi < 4; ++mi) af[mi] = rd32(as, wm + mi * 16 + col, quad);
#pragma unroll
        for (int ni = 0; ni < 4; ++ni) bfr[ni] = rd32(bs, wn + ni * 16 + col, quad);
#pragma unroll
        for (int mi = 0; mi < 4; ++mi)
#pragma unroll
            for (int ni = 0; ni < 4; ++ni)
                acc[mi][ni] = MFMA16(af[mi], bfr[ni], acc[mi][ni]);
    }
    epilogue<EPI, 4>(acc, m0, n0, wm, wn, col, quad, Cf, Cb, ldc, bias, res);
}

// ---------------------------------------------------------------------------
// gemm_deep: 256x256 tile, 8 waves (512 thr), BK=64 in two 32-wide k-halves,
// LDS 128 KB (1 block/CU), 4 phases per K-tile, counted per-half vmcnt.
// Optional split-K via blockIdx.z.
// ---------------------------------------------------------------------------
template <int EPI>
__global__ __launch_bounds__(512, 2) void gemm_deep(const bf16* __restrict__ A, int lda,
                                                    const bf16* __restrict__ B, int ldb, int K,
                                                    bf16* __restrict__ Cb, int ldc,
                                                    const float* __restrict__ bias) {
    __shared__ __align__(16) bf16 As[2][2][256 * 32];
    __shared__ __align__(16) bf16 Bs[2][2][256 * 32];
    const int tid = threadIdx.x, wave = tid >> 6, lane = tid & 63;
    const int gx = gridDim.x;
    const int orig = blockIdx.y * gx + blockIdx.x;
    const int cpx = (gx * gridDim.y) >> 3;
    const int swz = (orig & 7) * cpx + (orig >> 3);
    const int m0 = (swz % gx) * 256, n0 = (swz / gx) * 256;
    // split-K offsets (no-op when gridDim.z == 1)
    A += (size_t)blockIdx.z * K;
    B += (size_t)blockIdx.z * K;
    Cb += (size_t)blockIdx.z * (size_t)gx * 256 * ldc;
    const int wm = (wave >> 2) * 128, wn = (wave & 3) * 64;
    const int col = lane & 15, quad = lane >> 4;
    const int cs8 = ((lane & 3) ^ ((lane >> 3) & 3)) * 8;

    floatx4 acc[8][4];
#pragma unroll
    for (int mi = 0; mi < 8; ++mi)
#pragma unroll
        for (int ni = 0; ni < 4; ++ni) acc[mi][ni] = (floatx4){0.f, 0.f, 0.f, 0.f};

    auto stA = [&](int buf, int kh, int kb) {
#pragma unroll
        for (int i = 0; i < 2; ++i) {
            int r0 = wave * 32 + i * 16;
            async16(A + (size_t)(m0 + r0 + (lane >> 2)) * lda + kb + kh * 32 + cs8,
                    As[buf][kh] + r0 * 32);
        }
    };
    auto stB = [&](int buf, int kh, int kb) {
#pragma unroll
        for (int i = 0; i < 2; ++i) {
            int r0 = wave * 32 + i * 16;
            async16(B + (size_t)(n0 + r0 + (lane >> 2)) * ldb + kb + kh * 32 + cs8,
                    Bs[buf][kh] + r0 * 32);
        }
    };

    const int nk = K / 64;
    stA(0, 0, 0); stB(0, 0, 0); stA(0, 1, 0); stB(0, 1, 0);
    asm volatile("s_waitcnt vmcnt(4)" ::: "memory");
    __builtin_amdgcn_s_barrier();

    for (int t = 0; t < nk; ++t) {
        const int c = t & 1, nb = c ^ 1;
        const bf16* a0 = As[c][0];
        const bf16* a1 = As[c][1];
        const bf16* b0s = Bs[c][0];
        const bf16* b1s = Bs[c][1];
        const int kb1 = (t + 1) * 64;
        const bool pre = (t + 1 < nk);
        bf16x8 bfr[4], af[4];

        // ---- p0: (k0, mh0) ----
        if (pre) stA(nb, 0, kb1);
#pragma unroll
        for (int ni = 0; ni < 4; ++ni) bfr[ni] = rd32(b0s, wn + ni * 16 + col, quad);
#pragma unroll
        for (int mi = 0; mi < 4; ++mi) af[mi] = rd32(a0, wm + mi * 16 + col, quad);
        __builtin_amdgcn_s_barrier();
        asm volatile("s_waitcnt lgkmcnt(0)" ::: "memory");
        __builtin_amdgcn_s_setprio(1);
#pragma unroll
        for (int mi = 0; mi < 4; ++mi)
#pragma unroll
            for (int ni = 0; ni < 4; ++ni)
                acc[mi][ni] = MFMA16(af[mi], bfr[ni], acc[mi][ni]);
        __builtin_amdgcn_s_setprio(0);
        __builtin_amdgcn_s_barrier();

        // ---- p1: (k0, mh1) ----
        if (pre) stB(nb, 0, kb1);
#pragma unroll
        for (int mi = 0; mi < 4; ++mi) af[mi] = rd32(a0, wm + 64 + mi * 16 + col, quad);
        __builtin_amdgcn_s_barrier();
        asm volatile("s_waitcnt lgkmcnt(0)" ::: "memory");
        __builtin_amdgcn_s_setprio(1);
#pragma unroll
        for (int mi = 0; mi < 4; ++mi)
#pragma unroll
            for (int ni = 0; ni < 4; ++ni)
                acc[mi + 4][ni] = MFMA16(af[mi], bfr[ni], acc[mi + 4][ni]);
        __builtin_amdgcn_s_setprio(0);
        if (pre) asm volatile("s_waitcnt vmcnt(4)" ::: "memory");
        else     asm volatile("s_waitcnt vmcnt(0)" ::: "memory");
        __builtin_amdgcn_s_barrier();

        // ---- p2: (k1, mh0) ----
        if (pre) stA(nb, 1, kb1);
#pragma unroll
        for (int ni = 0; ni < 4; ++ni) bfr[ni] = rd32(b1s, wn + ni * 16 + col, quad);
#pragma unroll
        for (int mi = 0; mi < 4; ++mi) af[mi] = rd32(a1, wm + mi * 16 + col, quad);
        __builtin_amdgcn_s_barrier();
        asm volatile("s_waitcnt lgkmcnt(0)" ::: "memory");
        __builtin_amdgcn_s_setprio(1);
#pragma unroll
        for (int mi = 0; mi < 4; ++mi)
#pragma unroll
            for (int ni = 0; ni < 4; ++ni)
                acc[mi][ni] = MFMA16(af[mi], bfr[ni], acc[mi][ni]);
        __builtin_amdgcn_s_setprio(0);
        __builtin_amdgcn_s_barrier();

        // ---- p3: (k1, mh1) ----
        if (pre) stB(nb, 1, kb1);
#pragma unroll
        for (int mi = 0; mi < 4; ++mi) af[mi] = rd32(a1, wm + 64 + mi * 16 + col, quad);
        __builtin_amdgcn_s_barrier();
        asm volatile("s_waitcnt lgkmcnt(0)" ::: "memory");
        __builtin_amdgcn_s_setprio(1);
#pragma unroll
        for (int mi = 0; mi < 4; ++mi)
#pragma unroll
            for (int ni = 0; ni < 4; ++ni)
                acc[mi + 4][ni] = MFMA16(af[mi], bfr[ni], acc[mi + 4][ni]);
        __builtin_amdgcn_s_setprio(0);
        if (pre) asm volatile("s_waitcnt vmcnt(4)" ::: "memory");
        else     asm volatile("s_waitcnt vmcnt(0)" ::: "memory");
        __builtin_amdgcn_s_barrier();
    }

#pragma unroll
    for (int mi = 0; mi < 8; ++mi)
#pragma unroll
        for (int ni = 0; ni < 4; ++ni)
#pragma unroll
            for (int r = 0; r < 4; ++r) {
                int row = m0 + wm + mi * 16 + quad * 4 + r;
                int cc = n0 + wn + ni * 16 + col;
                size_t idx = (size_t)row * ldc + cc;
                float v = acc[mi][ni][r];
                if constexpr (EPI == 2) {
                    v += bias[cc];
                    v = fmaxf(v, 0.f);
                    Cb[idx] = (bf16)v;
                } else {
                    Cb[idx] = (bf16)v;
                }
            }
}

// ---------------------------------------------------------------------------
// mlp2_reduce: out += p0+p1+p2+p3 + bout  (bf16 partials).
// ---------------------------------------------------------------------------
__global__ __launch_bounds__(256) void mlp2_reduce(const bf16* __restrict__ p,
                                                   const float* __restrict__ bout,
                                                   float* __restrict__ out) {
    int i = (blockIdx.x * 256 + threadIdx.x) * 4;
    float4 o = *(const float4*)(out + i);
    float4 bb = *(const float4*)(bout + (i & 1023));
    float s0 = 0.f, s1 = 0.f, s2 = 0.f, s3 = 0.f;
#pragma unroll
    for (int z = 0; z < 4; ++z) {
        bf16x4 v = *(const bf16x4*)(p + (size_t)z * 4194304 + i);
        s0 += (float)v[0];
        s1 += (float)v[1];
        s2 += (float)v[2];
        s3 += (float)v[3];
    }
    o.x += s0 + bb.x;
    o.y += s1 + bb.y;
    o.z += s2 + bb.z;
    o.w += s3 + bb.w;
    *(float4*)(out + i) = o;
}

// ---------------------------------------------------------------------------
// gemm_pipe64: 128x64 tile, BK=64, 3-stage pipeline, counted vmcnt(6),
// XCD-chunked. rd64-family swizzle (conflict-free). Used for WO.
// ---------------------------------------------------------------------------
template <int EPI>
__global__ __launch_bounds__(256) void gemm_pipe64(const bf16* __restrict__ A, int lda,
                                                   const bf16* __restrict__ B, int ldb, int K,
                                                   float* __restrict__ Cf, bf16* __restrict__ Cb,
                                                   int ldc, const float* __restrict__ bias,
                                                   const float* __restrict__ res) {
    __shared__ __align__(16) bf16 As[3][128 * 64];
    __shared__ __align__(16) bf16 Bs[3][64 * 64];
    const int tid = threadIdx.x, wave = tid >> 6, lane = tid & 63;
    const int orig = blockIdx.y * 16 + blockIdx.x;
    const int wgid = (orig & 7) * 64 + (orig >> 3);
    const int m0 = (wgid >> 4) * 128, n0 = (wgid & 15) * 64;
    const int wm = (wave >> 1) * 64, wn = (wave & 1) * 32;
    const int col = lane & 15, quad = lane >> 4;
    const int rsub = lane >> 3;
    const int csub = ((lane & 7) ^ rsub) * 8;

    floatx4 acc[4][2];
#pragma unroll
    for (int mi = 0; mi < 4; ++mi)
#pragma unroll
        for (int ni = 0; ni < 2; ++ni) acc[mi][ni] = (floatx4){0.f, 0.f, 0.f, 0.f};

    auto stage = [&](int buf, int k0) {
#pragma unroll
        for (int i = 0; i < 4; ++i) {
            int r0 = wave * 32 + i * 8;
            async16(A + (size_t)(m0 + r0 + rsub) * lda + k0 + csub, As[buf] + r0 * 64);
        }
#pragma unroll
        for (int i = 0; i < 2; ++i) {
            int r0 = wave * 16 + i * 8;
            async16(B + (size_t)(n0 + r0 + rsub) * ldb + k0 + csub, Bs[buf] + r0 * 64);
        }
    };

    const int nk = K / 64;
    stage(0, 0);
    stage(1, 64);
    for (int it = 0; it < nk; ++it) {
        if (it + 1 < nk) asm volatile("s_waitcnt vmcnt(6)" ::: "memory");
        else             asm volatile("s_waitcnt vmcnt(0)" ::: "memory");
        __builtin_amdgcn_s_barrier();
        if (it + 2 < nk) stage((it + 2) % 3, (it + 2) * 64);

        const bf16* as = As[it % 3];
        const bf16* bs = Bs[it % 3];
#pragma unroll
        for (int ks = 0; ks < 2; ++ks) {
            bf16x8 af[4], bfr[2];
#pragma unroll
            for (int mi = 0; mi < 4; ++mi) {
                int row = wm + mi * 16 + col;
                af[mi] = *(const bf16x8*)&as[row * 64 + (((ks * 4 + quad) ^ (row & 7)) * 8)];
            }
#pragma unroll
            for (int ni = 0; ni < 2; ++ni) {
                int row = wn + ni * 16 + col;
                bfr[ni] = *(const bf16x8*)&bs[row * 64 + (((ks * 4 + quad) ^ (row & 7)) * 8)];
            }
#pragma unroll
            for (int mi = 0; mi < 4; ++mi)
#pragma unroll
                for (int ni = 0; ni < 2; ++ni)
                    acc[mi][ni] = MFMA16(af[mi], bfr[ni], acc[mi][ni]);
        }
    }
    epilogue<EPI, 2>(acc, m0, n0, wm, wn, col, quad, Cf, Cb, ldc, bias, res);
}

// ---------------------------------------------------------------------------
// Transpose V, folding in the softmax denominator: vt[h][c] = V[c][h] / l_c.
// ---------------------------------------------------------------------------
__global__ __launch_bounds__(256) void transpose_v(const bf16* __restrict__ qkv,
                                                   const float* __restrict__ linv,
                                                   bf16* __restrict__ vt) {
    __shared__ bf16 t[64][65];
    const int bh = blockIdx.y, ct = blockIdx.x;
    const int b = bh >> 4, a = bh & 15;
    const float* lv = linv + (size_t)bh * 2048 + ct * 64;
    for (int idx = threadIdx.x; idx < 4096; idx += 256) {
        int c = idx >> 6, h = idx & 63;
        float v = (float)qkv[(size_t)(b * 2048 + ct * 64 + c) * 3072 + 2048 + a * 64 + h];
        t[h][c] = (bf16)(v * lv[c]);
    }
    __syncthreads();
    for (int idx = threadIdx.x; idx < 4096; idx += 256) {
        int h = idx >> 6, c = idx & 63;
        vt[(size_t)(bh * 64 + h) * 2048 + ct * 64 + c] = t[h][c];
    }
}

// ---------------------------------------------------------------------------
// Attention pass 1 (R14): 128 c-rows per block, 8 waves (512 thr).
// l_c = sum_{C<=c} exp(S/8); stores linv[c] = 1/l_c.
// R14: XCD-chunked block remap (512 blocks = 64 x 8): each XCD owns 4
// complete bh-rows (all 16 tiles) -> that head's K/Q panels stay in its L2.
// ---------------------------------------------------------------------------
__global__ __launch_bounds__(512, 4) void attn_stats(const bf16* __restrict__ qkv,
                                                     float* __restrict__ linv) {
    __shared__ __align__(16) bf16 Kt[128 * 64];   // 16 KB
    __shared__ __align__(16) bf16 Qt[3][64 * 64]; // 24 KB
    __shared__ float red[4][32];                  // cross-qh combine
    const int flat = blockIdx.y * 16 + blockIdx.x;
    const int swz = (flat & 7) * 64 + (flat >> 3);   // R14 XCD chunking
    const int bh = swz >> 4;
    const int xx = swz & 15;
    const int t = (xx & 1) ? (15 - (xx >> 1)) : (xx >> 1);
    const int b = bh >> 4, a = bh & 15;
    const int tid = threadIdx.x, wave = tid >> 6, lane = tid & 63;
    const int l31 = lane & 31, lh = lane >> 5;
    const int kq = wave & 3, qh = wave >> 2;
    const bf16* base = qkv + (size_t)b * 2048 * 3072;
    const int c0 = t * 128;
    const int niter = 2 * t + 2;

    stage64s(base + (size_t)c0 * 3072 + 1024 + a * 64, 3072, Kt, wave, lane);
    stage64q(base + a * 64, 3072, Qt[0], wave, lane);
    stage64q(base + (size_t)64 * 3072 + a * 64, 3072, Qt[1], wave, lane);

    float lrun[16];
#pragma unroll
    for (int r = 0; r < 16; ++r) lrun[r] = 0.f;
    bf16x8 kf[4];

    for (int i = 0; i < niter; ++i) {
        if (i + 1 < niter) asm volatile("s_waitcnt vmcnt(1)" ::: "memory");
        else               asm volatile("s_waitcnt vmcnt(0)" ::: "memory");
        __builtin_amdgcn_s_barrier();
        if (i + 2 < niter)
            stage64q(base + (size_t)(i + 2) * 64 * 3072 + a * 64, 3072,
                     Qt[(i + 2) % 3], wave, lane);
        if (i == 0) {
#pragma unroll
            for (int s = 0; s < 4; ++s) kf[s] = rd64(Kt, 32 * kq + l31, 2 * s + lh);
        }
        const bf16* q = Qt[i % 3];
        bf16x8 qf0 = rd64(q, 32 * qh + l31, 0 + lh);
        bf16x8 qf1 = rd64(q, 32 * qh + l31, 2 + lh);
        bf16x8 qf2 = rd64(q, 32 * qh + l31, 4 + lh);
        bf16x8 qf3 = rd64(q, 32 * qh + l31, 6 + lh);
        floatx16 s0 = (floatx16)0.f, s1 = (floatx16)0.f;
        __builtin_amdgcn_s_setprio(1);
        s0 = MFMA32(kf[0], qf0, s0);
        s1 = MFMA32(kf[2], qf2, s1);
        s0 = MFMA32(kf[1], qf1, s0);
        s1 = MFMA32(kf[3], qf3, s1);
        __builtin_amdgcn_s_setprio(0);
#pragma unroll
        for (int r = 0; r < 16; ++r) {
            float e = __builtin_amdgcn_exp2f((s0[r] + s1[r]) * K2);
            if (i >= niter - 2) {
                int Crel = 64 * (i - 2 * t) + 32 * qh + l31;
                int crel = 32 * kq + (r & 3) + 8 * (r >> 2) + 4 * lh;
                if (Crel > crel) e = 0.f;
            }
            lrun[r] += e;
        }
    }
#pragma unroll
    for (int r = 0; r < 16; ++r) {
        float v = lrun[r];
        v += __shfl_xor(v, 1);
        v += __shfl_xor(v, 2);
        v += __shfl_xor(v, 4);
        v += __shfl_xor(v, 8);
        v += __shfl_xor(v, 16);
        lrun[r] = v;
    }
    if (qh == 1 && l31 == 0) {
#pragma unroll
        for (int r = 0; r < 16; ++r)
            red[kq][(r & 3) + 8 * (r >> 2) + 4 * lh] = lrun[r];
    }
    __syncthreads();
    if (qh == 0 && l31 == 0) {
#pragma unroll
        for (int r = 0; r < 16; ++r) {
            int cr = (r & 3) + 8 * (r >> 2) + 4 * lh;
            linv[(size_t)bh * 2048 + c0 + 32 * kq + cr] = 1.0f / (lrun[r] + red[kq][cr]);
        }
    }
}

// ---------------------------------------------------------------------------
// Attention pass 2 (R13+R14): 128 C-rows per block, 8 waves (512 thr).
// z[C][h] = sum_{c>=C} exp2(S[c][C]*K2) * V'[c][h]  (V' = V/l_c prefolded).
// pi-staged K (no cross-lane exchange); R14: XCD-chunked block remap so each
// XCD keeps 4 heads' K/V'/Q panels L2-resident.
// ---------------------------------------------------------------------------
__global__ __launch_bounds__(512, 4) void attn_av(const bf16* __restrict__ qkv,
                                                  const bf16* __restrict__ vt,
                                                  bf16* __restrict__ zb) {
    __shared__ __align__(16) char smem[65536];
    bf16* Qt = (bf16*)smem;             // 16 KB, 128 rows
    bf16* Kt = (bf16*)(smem + 16384);   // 3 x 8 KB
    bf16* Vt = (bf16*)(smem + 40960);   // 3 x 8 KB
    const int flat = blockIdx.y * 16 + blockIdx.x;
    const int swz = (flat & 7) * 64 + (flat >> 3);   // R14 XCD chunking
    const int bh = swz >> 4;
    const int xx = swz & 15;
    const int t = (xx & 1) ? (15 - (xx >> 1)) : (xx >> 1);
    const int b = bh >> 4, a = bh & 15;
    const int tid = threadIdx.x, wave = tid >> 6, lane = tid & 63;
    const int l31 = lane & 31, lh = lane >> 5;
    const int Cq = wave & 3, cq = wave >> 2;
    const bf16* base = qkv + (size_t)b * 2048 * 3072;
    const int C0 = t * 128;
    const int niter = 32 - 2 * t;

    stage64s(base + (size_t)C0 * 3072 + a * 64, 3072, Qt, wave, lane);  // 128 Q rows
    stage64p(base + (size_t)(2 * t) * 64 * 3072 + 1024 + a * 64, 3072, Kt, wave, lane);
    stage64q(vt + (size_t)bh * 64 * 2048 + 2 * t * 64, 2048, Vt, wave, lane);
    stage64p(base + (size_t)(2 * t + 1) * 64 * 3072 + 1024 + a * 64, 3072, Kt + 4096, wave, lane);
    stage64q(vt + (size_t)bh * 64 * 2048 + (2 * t + 1) * 64, 2048, Vt + 4096, wave, lane);

    floatx16 zacc[2];
    zacc[0] = (floatx16)0.f;
    zacc[1] = (floatx16)0.f;
    bf16x8 qf[4];

    for (int i = 0; i < niter; ++i) {
        const int ct = 2 * t + i;
        if (i + 1 < niter) asm volatile("s_waitcnt vmcnt(2)" ::: "memory");
        else               asm volatile("s_waitcnt vmcnt(0)" ::: "memory");
        __builtin_amdgcn_s_barrier();
        if (i + 2 < niter) {
            stage64p(base + (size_t)(ct + 2) * 64 * 3072 + 1024 + a * 64, 3072,
                     Kt + ((i + 2) % 3) * 4096, wave, lane);
            stage64q(vt + (size_t)bh * 64 * 2048 + (ct + 2) * 64, 2048,
                     Vt + ((i + 2) % 3) * 4096, wave, lane);
        }
        if (i == 0) {
#pragma unroll
            for (int s = 0; s < 4; ++s) qf[s] = rd64(Qt, 32 * Cq + l31, 2 * s + lh);
        }
        const bf16* kt = Kt + (i % 3) * 4096;
        const bf16* vts = Vt + (i % 3) * 4096;

        // S'[pi-row, C] quadrant: A = permuted K rows (32cq + l31), B = Q rows
        floatx16 s0 = (floatx16)0.f, s1 = (floatx16)0.f;
        __builtin_amdgcn_s_setprio(1);
        s0 = MFMA32(rd64(kt, 32 * cq + l31, 0 + lh), qf[0], s0);
        s1 = MFMA32(rd64(kt, 32 * cq + l31, 4 + lh), qf[2], s1);
        s0 = MFMA32(rd64(kt, 32 * cq + l31, 2 + lh), qf[1], s0);
        s1 = MFMA32(rd64(kt, 32 * cq + l31, 6 + lh), qf[3], s1);
        __builtin_amdgcn_s_setprio(0);

        // reg r holds c = 64*i + 32*cq + pi(c_off); pi-adjusted:
        // crel = (r&3) + ((r>>2)&1)*4 + lh*8 + (r>>3)*16
        float p[16];
#pragma unroll
        for (int r = 0; r < 16; ++r) {
            float e = __builtin_amdgcn_exp2f((s0[r] + s1[r]) * K2);
            if (i < 2) {
                int Crel = 32 * Cq + l31;
                int crel = 64 * i + 32 * cq + (r & 3) + (((r >> 2) & 1) << 2) +
                           (lh << 3) + (((r >> 3) & 1) << 4);
                if (Crel > crel) e = 0.f;
            }
            p[r] = e;
        }

        // Permuted S' registers are ALREADY the PV A-fragments: direct pack.
        bf16x8 pa[2];
#pragma unroll
        for (int g = 0; g < 2; ++g) {
            union { uint u[4]; bf16x8 v; } cv;
            cv.u[0] = pk2(p[8 * g + 0], p[8 * g + 1]);
            cv.u[1] = pk2(p[8 * g + 2], p[8 * g + 3]);
            cv.u[2] = pk2(p[8 * g + 4], p[8 * g + 5]);
            cv.u[3] = pk2(p[8 * g + 6], p[8 * g + 7]);
            pa[g] = cv.v;
        }

        // z[C, h] += P'[C, c] * V'[c, h]
        __builtin_amdgcn_s_setprio(1);
#pragma unroll
        for (int ht = 0; ht < 2; ++ht) {
#pragma unroll
            for (int s = 0; s < 2; ++s) {
                bf16x8 vf = rd64(vts, 32 * ht + l31, 4 * cq + 2 * s + lh);
                zacc[ht] = MFMA32(pa[s], vf, zacc[ht]);
            }
        }
        __builtin_amdgcn_s_setprio(0);
    }

    __syncthreads();
    float* Zex = (float*)smem;
    if (cq == 1) {
#pragma unroll
        for (int ht = 0; ht < 2; ++ht)
#pragma unroll
            for (int q = 0; q < 4; ++q) {
                float4 t4 = {zacc[ht][4 * q + 0], zacc[ht][4 * q + 1],
                             zacc[ht][4 * q + 2], zacc[ht][4 * q + 3]};
                *(float4*)&Zex[Cq * 2048 + lane * 32 + (((ht * 4 + q) ^ (lane & 7)) * 4)] = t4;
            }
    }
    __syncthreads();
    if (cq == 0) {
#pragma unroll
        for (int ht = 0; ht < 2; ++ht)
#pragma unroll
            for (int q = 0; q < 4; ++q) {
                float4 t4 = *(const float4*)&Zex[Cq * 2048 + lane * 32 +
                                                 (((ht * 4 + q) ^ (lane & 7)) * 4)];
                zacc[ht][4 * q + 0] += t4.x;
                zacc[ht][4 * q + 1] += t4.y;
                zacc[ht][4 * q + 2] += t4.z;
                zacc[ht][4 * q + 3] += t4.w;
            }
#pragma unroll
        for (int ht = 0; ht < 2; ++ht)
#pragma unroll
            for (int r = 0; r < 16; ++r) {
                int Cg = C0 + 32 * Cq + (r & 3) + 8 * (r >> 2) + 4 * lh;
                zb[(size_t)(b * 2048 + Cg) * 1024 + a * 64 + 32 * ht + l31] =
                    (bf16)zacc[ht][r];
            }
    }
}

// ---------------------------------------------------------------------------
// Host launcher
// ---------------------------------------------------------------------------
extern "C" void kernel_launch(void* const* d_in, const int* in_sizes, int n_in,
                              void* d_out, int out_size, void* d_ws, size_t ws_size,
                              hipStream_t stream) {
    (void)in_sizes; (void)n_in; (void)out_size; (void)ws_size;
    const float* x    = (const float*)d_in[0];
    const float* WK   = (const float*)d_in[1];
    const float* WQ   = (const float*)d_in[2];
    const float* WV   = (const float*)d_in[3];
    const float* WO   = (const float*)d_in[4];
    const float* Win  = (const float*)d_in[5];
    const float* bin  = (const float*)d_in[6];
    const float* Wout = (const float*)d_in[7];
    const float* bout = (const float*)d_in[8];
    float* out = (float*)d_out;

    char* ws = (char*)d_ws;
    bf16*  xb   = (bf16*)(ws + 0);          //  8 MB
    bf16*  wqkv = (bf16*)(ws + 8388608);    //  6 MB
    bf16*  wo   = (bf16*)(ws + 14680064);   //  2 MB
    bf16*  win  = (bf16*)(ws + 16777216);   //  8 MB
    bf16*  wout = (bf16*)(ws + 25165824);   //  8 MB
    bf16*  qkvb = (bf16*)(ws + 33554432);   // 24 MB (dead after attn)
    bf16*  vtb  = (bf16*)(ws + 58720256);   //  8 MB (dead after attn)
    float* mst  = (float*)(ws + 67108864);  // 256 KB (linv)
    bf16*  zbuf = (bf16*)(ws + 67633152);   //  8 MB
    bf16*  xmid = (bf16*)(ws + 76021760);   //  8 MB
    bf16*  hbuf = (bf16*)(ws + 84410368);   // 32 MB
    bf16*  partb = (bf16*)(ws + 33554432);  // 32 MB = 4 x 8 MB bf16 partials
                                            // (aliases qkvb+vtb, dead by MLP2)

    cvt_all<<<16384, 256, 0, stream>>>(x, WQ, WK, WV, WO, Win, Wout,
                                       xb, wqkv, wo, win, wout);

    // QKV: [4096x1024] x [3072x1024]^T (3 blocks/CU -> pipe)
    gemm_pipe<0><<<dim3(24, 32), 256, 0, stream>>>(xb, 1024, wqkv, 1024, 1024,
                                                   nullptr, qkvb, 3072, nullptr, nullptr);
    attn_stats<<<dim3(16, 32), 512, 0, stream>>>(qkvb, mst);
    transpose_v<<<dim3(32, 32), 256, 0, stream>>>(qkvb, mst, vtb);
    attn_av<<<dim3(16, 32), 512, 0, stream>>>(qkvb, vtb, zbuf);
    // WO: z @ W_O^T + x (pipelined BK=64, XCD-chunked)
    gemm_pipe64<1><<<dim3(16, 32), 256, 0, stream>>>(zbuf, 1024, wo, 1024, 1024,
                                                     out, xmid, 1024, nullptr, x);
    // MLP1: relu(xmid @ W_in^T + b_in) — 256^2 4-phase deep-pipe, 1 block/CU
    gemm_deep<2><<<dim3(16, 16), 512, 0, stream>>>(xmid, 1024, win, 1024, 1024,
                                                   hbuf, 4096, bin);
    // MLP2: 256^2 4-phase deep-pipe, split-K=4 (256 blocks = 1/CU), bf16
    // partials into dead attn buffers, then fused reduce (+b_out).
    gemm_deep<0><<<dim3(16, 4, 4), 512, 0, stream>>>(hbuf, 4096, wout, 4096, 1024,
                                                     partb, 1024, nullptr);
    mlp2_reduce<<<4096, 256, 0, stream>>>(partb, bout, out);
}

// Round 15
// 356.469 us; speedup vs baseline: 1.0244x; 1.0123x over previous
//
#include <hip/hip_runtime.h>
#include <hip/hip_bf16.h>
#include <cstdint>
#include <cstddef>

typedef __bf16 bf16;
typedef bf16 bf16x4 __attribute__((ext_vector_type(4)));
typedef bf16 bf16x8 __attribute__((ext_vector_type(8)));
typedef float floatx4 __attribute__((ext_vector_type(4)));
typedef float floatx16 __attribute__((ext_vector_type(16)));
typedef unsigned int uint;

#define MFMA16(a, b, c) __builtin_amdgcn_mfma_f32_16x16x32_bf16((a), (b), (c), 0, 0, 0)
#define MFMA32(a, b, c) __builtin_amdgcn_mfma_f32_32x32x16_bf16((a), (b), (c), 0, 0, 0)

// log2(e)/8: S is the RAW k.q dot; softmax uses exp(S/8) = exp2(S*K2)
#define K2 0.18033688011112042f

__device__ __forceinline__ void async16(const void* g, void* l) {
    __builtin_amdgcn_global_load_lds((const __attribute__((address_space(1))) void*)g,
                                     (__attribute__((address_space(3))) void*)l,
                                     16, 0, 0);
}

// swizzled tile stage: each wave stages 16 rows (2 async16). wave in 0..3 -> 64
// rows; wave in 0..7 -> 128 rows.
__device__ __forceinline__ void stage64s(const bf16* g0, int ldg, bf16* lds, int wave, int lane) {
#pragma unroll
    for (int i = 0; i < 2; ++i) {
        int r0 = wave * 16 + i * 8;  // wave-uniform
        async16(g0 + (size_t)(r0 + (lane >> 3)) * ldg + ((lane & 7) ^ (lane >> 3)) * 8,
                lds + r0 * 64);
    }
}
// 8-wave stage of a 64-row tile: each wave stages 8 rows (1 async16).
__device__ __forceinline__ void stage64q(const bf16* g0, int ldg, bf16* lds, int wave, int lane) {
    int r0 = wave * 8;  // wave-uniform
    async16(g0 + (size_t)(r0 + (lane >> 3)) * ldg + ((lane & 7) ^ (lane >> 3)) * 8,
            lds + r0 * 64);
}
// R13: K-row-permuted stage — LDS row j holds GLOBAL row pi(j), pi = swap
// bits 2,3 of j. S' = MFMA(piK, Q) lands registers directly in the PV
// A-fragment layout (contraction over c is permutation-invariant).
__device__ __forceinline__ void stage64p(const bf16* g0, int ldg, bf16* lds, int wave, int lane) {
    int j = wave * 8 + (lane >> 3);
    int pj = (j & ~12) | ((j & 4) << 1) | ((j & 8) >> 1);
    async16(g0 + (size_t)pj * ldg + ((lane & 7) ^ (lane >> 3)) * 8,
            lds + wave * 8 * 64);
}
__device__ __forceinline__ bf16x8 rd64(const bf16* t, int row, int chunk) {
    return *(const bf16x8*)&t[row * 64 + ((chunk ^ (row & 7)) * 8)];
}
// R12: chunk XOR uses (row>>1)&3 — 2-way (free) instead of 4-way conflicts.
__device__ __forceinline__ bf16x8 rd32(const bf16* t, int row, int quad) {
    return *(const bf16x8*)&t[row * 32 + ((quad ^ ((row >> 1) & 3)) * 8)];
}

// pack two f32 -> one u32 of 2 bf16
__device__ __forceinline__ uint pk2(float lo, float hi) {
    union { bf16 h[2]; uint u; } c;
    c.h[0] = (bf16)lo;
    c.h[1] = (bf16)hi;
    return c.u;
}

// ---------------------------------------------------------------------------
// Fused fp32->bf16 convert
// ---------------------------------------------------------------------------
__global__ __launch_bounds__(256) void cvt_all(const float* __restrict__ x,
                                               const float* __restrict__ WQ,
                                               const float* __restrict__ WK,
                                               const float* __restrict__ WV,
                                               const float* __restrict__ WO,
                                               const float* __restrict__ Win,
                                               const float* __restrict__ Wout,
                                               bf16* __restrict__ xb,
                                               bf16* __restrict__ wqkv,
                                               bf16* __restrict__ wo,
                                               bf16* __restrict__ win,
                                               bf16* __restrict__ wout) {
    int blk = blockIdx.x;
    const float* src;
    bf16* dst;
    int off;
    if (blk < 1024)      { src = WQ;   dst = wqkv;           off = blk; }
    else if (blk < 2048) { src = WK;   dst = wqkv + 1048576; off = blk - 1024; }
    else if (blk < 3072) { src = WV;   dst = wqkv + 2097152; off = blk - 2048; }
    else if (blk < 4096) { src = WO;   dst = wo;             off = blk - 3072; }
    else if (blk < 8192) { src = Win;  dst = win;            off = blk - 4096; }
    else if (blk < 12288){ src = Wout; dst = wout;           off = blk - 8192; }
    else                 { src = x;    dst = xb;             off = blk - 12288; }
    int i = off * 1024 + threadIdx.x * 4;
    float4 v = *(const float4*)(src + i);
    bf16x4 o = {(bf16)v.x, (bf16)v.y, (bf16)v.z, (bf16)v.w};
    *(bf16x4*)(dst + i) = o;
}

// ---------------------------------------------------------------------------
// Epilogue shared by the GEMM templates.
// ---------------------------------------------------------------------------
template <int EPI, int NACC>
__device__ __forceinline__ void epilogue(floatx4 (&acc)[4][NACC], int m0, int n0,
                                         int wm, int wn, int col, int quad,
                                         float* Cf, bf16* Cb, int ldc,
                                         const float* bias, const float* res) {
#pragma unroll
    for (int mi = 0; mi < 4; ++mi)
#pragma unroll
        for (int ni = 0; ni < NACC; ++ni)
#pragma unroll
            for (int r = 0; r < 4; ++r) {
                int row = m0 + wm + mi * 16 + quad * 4 + r;
                int cc = n0 + wn + ni * 16 + col;
                size_t idx = (size_t)row * ldc + cc;
                float v = acc[mi][ni][r];
                if constexpr (EPI == 0) {
                    Cb[idx] = (bf16)v;
                } else if constexpr (EPI == 1) {
                    v += res[idx];
                    Cf[idx] = v;
                    Cb[idx] = (bf16)v;
                } else if constexpr (EPI == 2) {
                    v += bias[cc];
                    v = fmaxf(v, 0.f);
                    Cb[idx] = (bf16)v;
                } else {
                    v += bias[cc] + Cf[idx];
                    Cf[idx] = v;
                }
            }
}

// ---------------------------------------------------------------------------
// gemm_pipe: 128x128 tile, BK=32, 3-stage LDS pipeline, fine vmcnt.
// ---------------------------------------------------------------------------
template <int EPI>
__global__ __launch_bounds__(256) void gemm_pipe(const bf16* __restrict__ A, int lda,
                                                 const bf16* __restrict__ B, int ldb, int K,
                                                 float* __restrict__ Cf, bf16* __restrict__ Cb,
                                                 int ldc, const float* __restrict__ bias,
                                                 const float* __restrict__ res) {
    __shared__ __align__(16) bf16 As[3][128 * 32];
    __shared__ __align__(16) bf16 Bs[3][128 * 32];
    const int tid = threadIdx.x, wave = tid >> 6, lane = tid & 63;
    const int m0 = blockIdx.y * 128, n0 = blockIdx.x * 128;
    const int wm = (wave >> 1) * 64, wn = (wave & 1) * 64;
    const int col = lane & 15, quad = lane >> 4;
    const int cs8 = ((lane & 3) ^ ((lane >> 3) & 3)) * 8;

    floatx4 acc[4][4];
#pragma unroll
    for (int mi = 0; mi < 4; ++mi)
#pragma unroll
        for (int ni = 0; ni < 4; ++ni) acc[mi][ni] = (floatx4){0.f, 0.f, 0.f, 0.f};

    auto stage = [&](int buf, int k0) {
#pragma unroll
        for (int i = 0; i < 2; ++i) {
            int r0 = wave * 32 + i * 16;
            async16(A + (size_t)(m0 + r0 + (lane >> 2)) * lda + k0 + cs8,
                    As[buf] + r0 * 32);
            async16(B + (size_t)(n0 + r0 + (lane >> 2)) * ldb + k0 + cs8,
                    Bs[buf] + r0 * 32);
        }
    };

    const int nk = K / 32;
    stage(0, 0);
    stage(1, 32);
    for (int it = 0; it < nk; ++it) {
        if (it + 1 < nk) asm volatile("s_waitcnt vmcnt(4)" ::: "memory");
        else             asm volatile("s_waitcnt vmcnt(0)" ::: "memory");
        __builtin_amdgcn_s_barrier();
        if (it + 2 < nk) stage((it + 2) % 3, (it + 2) * 32);

        const bf16* as = As[it % 3];
        const bf16* bs = Bs[it % 3];
        bf16x8 af[4], bfr[4];
#pragma unroll
        for (int mi = 0; mi < 4; ++mi) af[mi] = rd32(as, wm + mi * 16 + col, quad);
#pragma unroll
        for (int ni = 0; ni < 4; ++ni) bfr[ni] = rd32(bs, wn + ni * 16 + col, quad);
#pragma unroll
        for (int mi = 0; mi < 4; ++mi)
#pragma unroll
            for (int ni = 0; ni < 4; ++ni)
                acc[mi][ni] = MFMA16(af[mi], bfr[ni], acc[mi][ni]);
    }
    epilogue<EPI, 4>(acc, m0, n0, wm, wn, col, quad, Cf, Cb, ldc, bias, res);
}

// ---------------------------------------------------------------------------
// gemm_deep: 256x256 tile, 8 waves (512 thr), BK=64 in two 32-wide k-halves,
// LDS 128 KB (1 block/CU), 4 phases per K-tile, counted per-half vmcnt.
// Optional split-K via blockIdx.z.
// ---------------------------------------------------------------------------
template <int EPI>
__global__ __launch_bounds__(512, 2) void gemm_deep(const bf16* __restrict__ A, int lda,
                                                    const bf16* __restrict__ B, int ldb, int K,
                                                    bf16* __restrict__ Cb, int ldc,
                                                    const float* __restrict__ bias) {
    __shared__ __align__(16) bf16 As[2][2][256 * 32];
    __shared__ __align__(16) bf16 Bs[2][2][256 * 32];
    const int tid = threadIdx.x, wave = tid >> 6, lane = tid & 63;
    const int gx = gridDim.x;
    const int orig = blockIdx.y * gx + blockIdx.x;
    const int cpx = (gx * gridDim.y) >> 3;
    const int swz = (orig & 7) * cpx + (orig >> 3);
    const int m0 = (swz % gx) * 256, n0 = (swz / gx) * 256;
    // split-K offsets (no-op when gridDim.z == 1)
    A += (size_t)blockIdx.z * K;
    B += (size_t)blockIdx.z * K;
    Cb += (size_t)blockIdx.z * (size_t)gx * 256 * ldc;
    const int wm = (wave >> 2) * 128, wn = (wave & 3) * 64;
    const int col = lane & 15, quad = lane >> 4;
    const int cs8 = ((lane & 3) ^ ((lane >> 3) & 3)) * 8;

    floatx4 acc[8][4];
#pragma unroll
    for (int mi = 0; mi < 8; ++mi)
#pragma unroll
        for (int ni = 0; ni < 4; ++ni) acc[mi][ni] = (floatx4){0.f, 0.f, 0.f, 0.f};

    auto stA = [&](int buf, int kh, int kb) {
#pragma unroll
        for (int i = 0; i < 2; ++i) {
            int r0 = wave * 32 + i * 16;
            async16(A + (size_t)(m0 + r0 + (lane >> 2)) * lda + kb + kh * 32 + cs8,
                    As[buf][kh] + r0 * 32);
        }
    };
    auto stB = [&](int buf, int kh, int kb) {
#pragma unroll
        for (int i = 0; i < 2; ++i) {
            int r0 = wave * 32 + i * 16;
            async16(B + (size_t)(n0 + r0 + (lane >> 2)) * ldb + kb + kh * 32 + cs8,
                    Bs[buf][kh] + r0 * 32);
        }
    };

    const int nk = K / 64;
    stA(0, 0, 0); stB(0, 0, 0); stA(0, 1, 0); stB(0, 1, 0);
    asm volatile("s_waitcnt vmcnt(4)" ::: "memory");
    __builtin_amdgcn_s_barrier();

    for (int t = 0; t < nk; ++t) {
        const int c = t & 1, nb = c ^ 1;
        const bf16* a0 = As[c][0];
        const bf16* a1 = As[c][1];
        const bf16* b0s = Bs[c][0];
        const bf16* b1s = Bs[c][1];
        const int kb1 = (t + 1) * 64;
        const bool pre = (t + 1 < nk);
        bf16x8 bfr[4], af[4];

        // ---- p0: (k0, mh0) ----
        if (pre) stA(nb, 0, kb1);
#pragma unroll
        for (int ni = 0; ni < 4; ++ni) bfr[ni] = rd32(b0s, wn + ni * 16 + col, quad);
#pragma unroll
        for (int mi = 0; mi < 4; ++mi) af[mi] = rd32(a0, wm + mi * 16 + col, quad);
        __builtin_amdgcn_s_barrier();
        asm volatile("s_waitcnt lgkmcnt(0)" ::: "memory");
        __builtin_amdgcn_s_setprio(1);
#pragma unroll
        for (int mi = 0; mi < 4; ++mi)
#pragma unroll
            for (int ni = 0; ni < 4; ++ni)
                acc[mi][ni] = MFMA16(af[mi], bfr[ni], acc[mi][ni]);
        __builtin_amdgcn_s_setprio(0);
        __builtin_amdgcn_s_barrier();

        // ---- p1: (k0, mh1) ----
        if (pre) stB(nb, 0, kb1);
#pragma unroll
        for (int mi = 0; mi < 4; ++mi) af[mi] = rd32(a0, wm + 64 + mi * 16 + col, quad);
        __builtin_amdgcn_s_barrier();
        asm volatile("s_waitcnt lgkmcnt(0)" ::: "memory");
        __builtin_amdgcn_s_setprio(1);
#pragma unroll
        for (int mi = 0; mi < 4; ++mi)
#pragma unroll
            for (int ni = 0; ni < 4; ++ni)
                acc[mi + 4][ni] = MFMA16(af[mi], bfr[ni], acc[mi + 4][ni]);
        __builtin_amdgcn_s_setprio(0);
        if (pre) asm volatile("s_waitcnt vmcnt(4)" ::: "memory");
        else     asm volatile("s_waitcnt vmcnt(0)" ::: "memory");
        __builtin_amdgcn_s_barrier();

        // ---- p2: (k1, mh0) ----
        if (pre) stA(nb, 1, kb1);
#pragma unroll
        for (int ni = 0; ni < 4; ++ni) bfr[ni] = rd32(b1s, wn + ni * 16 + col, quad);
#pragma unroll
        for (int mi = 0; mi < 4; ++mi) af[mi] = rd32(a1, wm + mi * 16 + col, quad);
        __builtin_amdgcn_s_barrier();
        asm volatile("s_waitcnt lgkmcnt(0)" ::: "memory");
        __builtin_amdgcn_s_setprio(1);
#pragma unroll
        for (int mi = 0; mi < 4; ++mi)
#pragma unroll
            for (int ni = 0; ni < 4; ++ni)
                acc[mi][ni] = MFMA16(af[mi], bfr[ni], acc[mi][ni]);
        __builtin_amdgcn_s_setprio(0);
        __builtin_amdgcn_s_barrier();

        // ---- p3: (k1, mh1) ----
        if (pre) stB(nb, 1, kb1);
#pragma unroll
        for (int mi = 0; mi < 4; ++mi) af[mi] = rd32(a1, wm + 64 + mi * 16 + col, quad);
        __builtin_amdgcn_s_barrier();
        asm volatile("s_waitcnt lgkmcnt(0)" ::: "memory");
        __builtin_amdgcn_s_setprio(1);
#pragma unroll
        for (int mi = 0; mi < 4; ++mi)
#pragma unroll
            for (int ni = 0; ni < 4; ++ni)
                acc[mi + 4][ni] = MFMA16(af[mi], bfr[ni], acc[mi + 4][ni]);
        __builtin_amdgcn_s_setprio(0);
        if (pre) asm volatile("s_waitcnt vmcnt(4)" ::: "memory");
        else     asm volatile("s_waitcnt vmcnt(0)" ::: "memory");
        __builtin_amdgcn_s_barrier();
    }

#pragma unroll
    for (int mi = 0; mi < 8; ++mi)
#pragma unroll
        for (int ni = 0; ni < 4; ++ni)
#pragma unroll
            for (int r = 0; r < 4; ++r) {
                int row = m0 + wm + mi * 16 + quad * 4 + r;
                int cc = n0 + wn + ni * 16 + col;
                size_t idx = (size_t)row * ldc + cc;
                float v = acc[mi][ni][r];
                if constexpr (EPI == 2) {
                    v += bias[cc];
                    v = fmaxf(v, 0.f);
                    Cb[idx] = (bf16)v;
                } else {
                    Cb[idx] = (bf16)v;
                }
            }
}

// ---------------------------------------------------------------------------
// mlp2_reduce: out += p0+p1+p2+p3 + bout  (bf16 partials).
// ---------------------------------------------------------------------------
__global__ __launch_bounds__(256) void mlp2_reduce(const bf16* __restrict__ p,
                                                   const float* __restrict__ bout,
                                                   float* __restrict__ out) {
    int i = (blockIdx.x * 256 + threadIdx.x) * 4;
    float4 o = *(const float4*)(out + i);
    float4 bb = *(const float4*)(bout + (i & 1023));
    float s0 = 0.f, s1 = 0.f, s2 = 0.f, s3 = 0.f;
#pragma unroll
    for (int z = 0; z < 4; ++z) {
        bf16x4 v = *(const bf16x4*)(p + (size_t)z * 4194304 + i);
        s0 += (float)v[0];
        s1 += (float)v[1];
        s2 += (float)v[2];
        s3 += (float)v[3];
    }
    o.x += s0 + bb.x;
    o.y += s1 + bb.y;
    o.z += s2 + bb.z;
    o.w += s3 + bb.w;
    *(float4*)(out + i) = o;
}

// ---------------------------------------------------------------------------
// gemm_pipe64: 128x64 tile, BK=64, 3-stage pipeline, counted vmcnt(6),
// XCD-chunked. rd64-family swizzle (conflict-free). Used for WO.
// ---------------------------------------------------------------------------
template <int EPI>
__global__ __launch_bounds__(256) void gemm_pipe64(const bf16* __restrict__ A, int lda,
                                                   const bf16* __restrict__ B, int ldb, int K,
                                                   float* __restrict__ Cf, bf16* __restrict__ Cb,
                                                   int ldc, const float* __restrict__ bias,
                                                   const float* __restrict__ res) {
    __shared__ __align__(16) bf16 As[3][128 * 64];
    __shared__ __align__(16) bf16 Bs[3][64 * 64];
    const int tid = threadIdx.x, wave = tid >> 6, lane = tid & 63;
    const int orig = blockIdx.y * 16 + blockIdx.x;
    const int wgid = (orig & 7) * 64 + (orig >> 3);
    const int m0 = (wgid >> 4) * 128, n0 = (wgid & 15) * 64;
    const int wm = (wave >> 1) * 64, wn = (wave & 1) * 32;
    const int col = lane & 15, quad = lane >> 4;
    const int rsub = lane >> 3;
    const int csub = ((lane & 7) ^ rsub) * 8;

    floatx4 acc[4][2];
#pragma unroll
    for (int mi = 0; mi < 4; ++mi)
#pragma unroll
        for (int ni = 0; ni < 2; ++ni) acc[mi][ni] = (floatx4){0.f, 0.f, 0.f, 0.f};

    auto stage = [&](int buf, int k0) {
#pragma unroll
        for (int i = 0; i < 4; ++i) {
            int r0 = wave * 32 + i * 8;
            async16(A + (size_t)(m0 + r0 + rsub) * lda + k0 + csub, As[buf] + r0 * 64);
        }
#pragma unroll
        for (int i = 0; i < 2; ++i) {
            int r0 = wave * 16 + i * 8;
            async16(B + (size_t)(n0 + r0 + rsub) * ldb + k0 + csub, Bs[buf] + r0 * 64);
        }
    };

    const int nk = K / 64;
    stage(0, 0);
    stage(1, 64);
    for (int it = 0; it < nk; ++it) {
        if (it + 1 < nk) asm volatile("s_waitcnt vmcnt(6)" ::: "memory");
        else             asm volatile("s_waitcnt vmcnt(0)" ::: "memory");
        __builtin_amdgcn_s_barrier();
        if (it + 2 < nk) stage((it + 2) % 3, (it + 2) * 64);

        const bf16* as = As[it % 3];
        const bf16* bs = Bs[it % 3];
#pragma unroll
        for (int ks = 0; ks < 2; ++ks) {
            bf16x8 af[4], bfr[2];
#pragma unroll
            for (int mi = 0; mi < 4; ++mi) {
                int row = wm + mi * 16 + col;
                af[mi] = *(const bf16x8*)&as[row * 64 + (((ks * 4 + quad) ^ (row & 7)) * 8)];
            }
#pragma unroll
            for (int ni = 0; ni < 2; ++ni) {
                int row = wn + ni * 16 + col;
                bfr[ni] = *(const bf16x8*)&bs[row * 64 + (((ks * 4 + quad) ^ (row & 7)) * 8)];
            }
#pragma unroll
            for (int mi = 0; mi < 4; ++mi)
#pragma unroll
                for (int ni = 0; ni < 2; ++ni)
                    acc[mi][ni] = MFMA16(af[mi], bfr[ni], acc[mi][ni]);
        }
    }
    epilogue<EPI, 2>(acc, m0, n0, wm, wn, col, quad, Cf, Cb, ldc, bias, res);
}

// ---------------------------------------------------------------------------
// Attention pass 1 (R15): 128 c-rows per block, 8 waves (512 thr).
// l_c = sum_{C<=c} exp(S/8). R15: transpose_v FUSED into the tail — this
// block computes linv for exactly the c-range whose V rows it transposes:
// vt[h][c] = V[c][h] * (1/l_c). linv never touches global memory; the
// separate transpose kernel (and its launch bubble) is gone. Transpose goes
// through a padded+XOR-swizzled LDS tile aliased onto the dead Qt buffer.
// R14 XCD chunking retained.
// ---------------------------------------------------------------------------
__global__ __launch_bounds__(512, 4) void attn_stats(const bf16* __restrict__ qkv,
                                                     bf16* __restrict__ vt) {
    __shared__ __align__(16) bf16 Kt[128 * 64];   // 16 KB
    __shared__ __align__(16) bf16 Qt[3][64 * 64]; // 24 KB (tail: transpose tile)
    __shared__ float red[4][32];                  // cross-qh combine
    __shared__ float linvS[128];                  // 1/l broadcast for the fuse
    const int flat = blockIdx.y * 16 + blockIdx.x;
    const int swz = (flat & 7) * 64 + (flat >> 3);   // R14 XCD chunking
    const int bh = swz >> 4;
    const int xx = swz & 15;
    const int t = (xx & 1) ? (15 - (xx >> 1)) : (xx >> 1);
    const int b = bh >> 4, a = bh & 15;
    const int tid = threadIdx.x, wave = tid >> 6, lane = tid & 63;
    const int l31 = lane & 31, lh = lane >> 5;
    const int kq = wave & 3, qh = wave >> 2;
    const bf16* base = qkv + (size_t)b * 2048 * 3072;
    const int c0 = t * 128;
    const int niter = 2 * t + 2;

    stage64s(base + (size_t)c0 * 3072 + 1024 + a * 64, 3072, Kt, wave, lane);
    stage64q(base + a * 64, 3072, Qt[0], wave, lane);
    stage64q(base + (size_t)64 * 3072 + a * 64, 3072, Qt[1], wave, lane);

    float lrun[16];
#pragma unroll
    for (int r = 0; r < 16; ++r) lrun[r] = 0.f;
    bf16x8 kf[4];

    for (int i = 0; i < niter; ++i) {
        if (i + 1 < niter) asm volatile("s_waitcnt vmcnt(1)" ::: "memory");
        else               asm volatile("s_waitcnt vmcnt(0)" ::: "memory");
        __builtin_amdgcn_s_barrier();
        if (i + 2 < niter)
            stage64q(base + (size_t)(i + 2) * 64 * 3072 + a * 64, 3072,
                     Qt[(i + 2) % 3], wave, lane);
        if (i == 0) {
#pragma unroll
            for (int s = 0; s < 4; ++s) kf[s] = rd64(Kt, 32 * kq + l31, 2 * s + lh);
        }
        const bf16* q = Qt[i % 3];
        bf16x8 qf0 = rd64(q, 32 * qh + l31, 0 + lh);
        bf16x8 qf1 = rd64(q, 32 * qh + l31, 2 + lh);
        bf16x8 qf2 = rd64(q, 32 * qh + l31, 4 + lh);
        bf16x8 qf3 = rd64(q, 32 * qh + l31, 6 + lh);
        floatx16 s0 = (floatx16)0.f, s1 = (floatx16)0.f;
        __builtin_amdgcn_s_setprio(1);
        s0 = MFMA32(kf[0], qf0, s0);
        s1 = MFMA32(kf[2], qf2, s1);
        s0 = MFMA32(kf[1], qf1, s0);
        s1 = MFMA32(kf[3], qf3, s1);
        __builtin_amdgcn_s_setprio(0);
#pragma unroll
        for (int r = 0; r < 16; ++r) {
            float e = __builtin_amdgcn_exp2f((s0[r] + s1[r]) * K2);
            if (i >= niter - 2) {
                int Crel = 64 * (i - 2 * t) + 32 * qh + l31;
                int crel = 32 * kq + (r & 3) + 8 * (r >> 2) + 4 * lh;
                if (Crel > crel) e = 0.f;
            }
            lrun[r] += e;
        }
    }
#pragma unroll
    for (int r = 0; r < 16; ++r) {
        float v = lrun[r];
        v += __shfl_xor(v, 1);
        v += __shfl_xor(v, 2);
        v += __shfl_xor(v, 4);
        v += __shfl_xor(v, 8);
        v += __shfl_xor(v, 16);
        lrun[r] = v;
    }
    if (qh == 1 && l31 == 0) {
#pragma unroll
        for (int r = 0; r < 16; ++r)
            red[kq][(r & 3) + 8 * (r >> 2) + 4 * lh] = lrun[r];
    }
    __syncthreads();
    if (qh == 0 && l31 == 0) {
#pragma unroll
        for (int r = 0; r < 16; ++r) {
            int cr = (r & 3) + 8 * (r >> 2) + 4 * lh;
            linvS[32 * kq + cr] = 1.0f / (lrun[r] + red[kq][cr]);
        }
    }
    __syncthreads();

    // ---- fused V transpose: vt[h][c0+cl] = V[c0+cl][h] * linvS[cl] ----
    // LDS tile [64 h][80 cols] (pad->16B-aligned rows), XOR swizzle on col
    // bits 3-5 by (h&7) to spread the scatter-write banks. Aliased on Qt.
    bf16 (*tT)[80] = (bf16(*)[80])Qt;
    const int th = tid >> 3;        // load: c within half; store: h row
    const int tc8 = (tid & 7) * 8;  // load: h chunk;      store: c chunk
#pragma unroll
    for (int half = 0; half < 2; ++half) {
        int cl = half * 64 + th;
        bf16x8 vv = *(const bf16x8*)(base + (size_t)(c0 + cl) * 3072 + 2048 +
                                     a * 64 + tc8);
        float sc = linvS[cl];
#pragma unroll
        for (int j = 0; j < 8; ++j)
            tT[tc8 + j][th ^ (j << 3)] = (bf16)((float)vv[j] * sc);
        __syncthreads();
        union { bf16x8 v; bf16 e[8]; } ov;
        ov.v = *(const bf16x8*)&tT[th][tc8 ^ ((th & 7) << 3)];
        *(bf16x8*)&vt[(size_t)(bh * 64 + th) * 2048 + c0 + half * 64 + tc8] = ov.v;
        __syncthreads();
    }
}

// ---------------------------------------------------------------------------
// Attention pass 2 (R13+R14): 128 C-rows per block, 8 waves (512 thr).
// z[C][h] = sum_{c>=C} exp2(S[c][C]*K2) * V'[c][h]  (V' = V/l_c prefolded).
// pi-staged K (no cross-lane exchange); XCD-chunked block remap.
// ---------------------------------------------------------------------------
__global__ __launch_bounds__(512, 4) void attn_av(const bf16* __restrict__ qkv,
                                                  const bf16* __restrict__ vt,
                                                  bf16* __restrict__ zb) {
    __shared__ __align__(16) char smem[65536];
    bf16* Qt = (bf16*)smem;             // 16 KB, 128 rows
    bf16* Kt = (bf16*)(smem + 16384);   // 3 x 8 KB
    bf16* Vt = (bf16*)(smem + 40960);   // 3 x 8 KB
    const int flat = blockIdx.y * 16 + blockIdx.x;
    const int swz = (flat & 7) * 64 + (flat >> 3);   // R14 XCD chunking
    const int bh = swz >> 4;
    const int xx = swz & 15;
    const int t = (xx & 1) ? (15 - (xx >> 1)) : (xx >> 1);
    const int b = bh >> 4, a = bh & 15;
    const int tid = threadIdx.x, wave = tid >> 6, lane = tid & 63;
    const int l31 = lane & 31, lh = lane >> 5;
    const int Cq = wave & 3, cq = wave >> 2;
    const bf16* base = qkv + (size_t)b * 2048 * 3072;
    const int C0 = t * 128;
    const int niter = 32 - 2 * t;

    stage64s(base + (size_t)C0 * 3072 + a * 64, 3072, Qt, wave, lane);  // 128 Q rows
    stage64p(base + (size_t)(2 * t) * 64 * 3072 + 1024 + a * 64, 3072, Kt, wave, lane);
    stage64q(vt + (size_t)bh * 64 * 2048 + 2 * t * 64, 2048, Vt, wave, lane);
    stage64p(base + (size_t)(2 * t + 1) * 64 * 3072 + 1024 + a * 64, 3072, Kt + 4096, wave, lane);
    stage64q(vt + (size_t)bh * 64 * 2048 + (2 * t + 1) * 64, 2048, Vt + 4096, wave, lane);

    floatx16 zacc[2];
    zacc[0] = (floatx16)0.f;
    zacc[1] = (floatx16)0.f;
    bf16x8 qf[4];

    for (int i = 0; i < niter; ++i) {
        const int ct = 2 * t + i;
        if (i + 1 < niter) asm volatile("s_waitcnt vmcnt(2)" ::: "memory");
        else               asm volatile("s_waitcnt vmcnt(0)" ::: "memory");
        __builtin_amdgcn_s_barrier();
        if (i + 2 < niter) {
            stage64p(base + (size_t)(ct + 2) * 64 * 3072 + 1024 + a * 64, 3072,
                     Kt + ((i + 2) % 3) * 4096, wave, lane);
            stage64q(vt + (size_t)bh * 64 * 2048 + (ct + 2) * 64, 2048,
                     Vt + ((i + 2) % 3) * 4096, wave, lane);
        }
        if (i == 0) {
#pragma unroll
            for (int s = 0; s < 4; ++s) qf[s] = rd64(Qt, 32 * Cq + l31, 2 * s + lh);
        }
        const bf16* kt = Kt + (i % 3) * 4096;
        const bf16* vts = Vt + (i % 3) * 4096;

        // S'[pi-row, C] quadrant: A = permuted K rows (32cq + l31), B = Q rows
        floatx16 s0 = (floatx16)0.f, s1 = (floatx16)0.f;
        __builtin_amdgcn_s_setprio(1);
        s0 = MFMA32(rd64(kt, 32 * cq + l31, 0 + lh), qf[0], s0);
        s1 = MFMA32(rd64(kt, 32 * cq + l31, 4 + lh), qf[2], s1);
        s0 = MFMA32(rd64(kt, 32 * cq + l31, 2 + lh), qf[1], s0);
        s1 = MFMA32(rd64(kt, 32 * cq + l31, 6 + lh), qf[3], s1);
        __builtin_amdgcn_s_setprio(0);

        // reg r holds c = 64*i + 32*cq + pi(c_off); pi-adjusted:
        // crel = (r&3) + ((r>>2)&1)*4 + lh*8 + (r>>3)*16
        float p[16];
#pragma unroll
        for (int r = 0; r < 16; ++r) {
            float e = __builtin_amdgcn_exp2f((s0[r] + s1[r]) * K2);
            if (i < 2) {
                int Crel = 32 * Cq + l31;
                int crel = 64 * i + 32 * cq + (r & 3) + (((r >> 2) & 1) << 2) +
                           (lh << 3) + (((r >> 3) & 1) << 4);
                if (Crel > crel) e = 0.f;
            }
            p[r] = e;
        }

        // Permuted S' registers are ALREADY the PV A-fragments: direct pack.
        bf16x8 pa[2];
#pragma unroll
        for (int g = 0; g < 2; ++g) {
            union { uint u[4]; bf16x8 v; } cv;
            cv.u[0] = pk2(p[8 * g + 0], p[8 * g + 1]);
            cv.u[1] = pk2(p[8 * g + 2], p[8 * g + 3]);
            cv.u[2] = pk2(p[8 * g + 4], p[8 * g + 5]);
            cv.u[3] = pk2(p[8 * g + 6], p[8 * g + 7]);
            pa[g] = cv.v;
        }

        // z[C, h] += P'[C, c] * V'[c, h]
        __builtin_amdgcn_s_setprio(1);
#pragma unroll
        for (int ht = 0; ht < 2; ++ht) {
#pragma unroll
            for (int s = 0; s < 2; ++s) {
                bf16x8 vf = rd64(vts, 32 * ht + l31, 4 * cq + 2 * s + lh);
                zacc[ht] = MFMA32(pa[s], vf, zacc[ht]);
            }
        }
        __builtin_amdgcn_s_setprio(0);
    }

    __syncthreads();
    float* Zex = (float*)smem;
    if (cq == 1) {
#pragma unroll
        for (int ht = 0; ht < 2; ++ht)
#pragma unroll
            for (int q = 0; q < 4; ++q) {
                float4 t4 = {zacc[ht][4 * q + 0], zacc[ht][4 * q + 1],
                             zacc[ht][4 * q + 2], zacc[ht][4 * q + 3]};
                *(float4*)&Zex[Cq * 2048 + lane * 32 + (((ht * 4 + q) ^ (lane & 7)) * 4)] = t4;
            }
    }
    __syncthreads();
    if (cq == 0) {
#pragma unroll
        for (int ht = 0; ht < 2; ++ht)
#pragma unroll
            for (int q = 0; q < 4; ++q) {
                float4 t4 = *(const float4*)&Zex[Cq * 2048 + lane * 32 +
                                                 (((ht * 4 + q) ^ (lane & 7)) * 4)];
                zacc[ht][4 * q + 0] += t4.x;
                zacc[ht][4 * q + 1] += t4.y;
                zacc[ht][4 * q + 2] += t4.z;
                zacc[ht][4 * q + 3] += t4.w;
            }
#pragma unroll
        for (int ht = 0; ht < 2; ++ht)
#pragma unroll
            for (int r = 0; r < 16; ++r) {
                int Cg = C0 + 32 * Cq + (r & 3) + 8 * (r >> 2) + 4 * lh;
                zb[(size_t)(b * 2048 + Cg) * 1024 + a * 64 + 32 * ht + l31] =
                    (bf16)zacc[ht][r];
            }
    }
}

// ---------------------------------------------------------------------------
// Host launcher
// ---------------------------------------------------------------------------
extern "C" void kernel_launch(void* const* d_in, const int* in_sizes, int n_in,
                              void* d_out, int out_size, void* d_ws, size_t ws_size,
                              hipStream_t stream) {
    (void)in_sizes; (void)n_in; (void)out_size; (void)ws_size;
    const float* x    = (const float*)d_in[0];
    const float* WK   = (const float*)d_in[1];
    const float* WQ   = (const float*)d_in[2];
    const float* WV   = (const float*)d_in[3];
    const float* WO   = (const float*)d_in[4];
    const float* Win  = (const float*)d_in[5];
    const float* bin  = (const float*)d_in[6];
    const float* Wout = (const float*)d_in[7];
    const float* bout = (const float*)d_in[8];
    float* out = (float*)d_out;

    char* ws = (char*)d_ws;
    bf16*  xb   = (bf16*)(ws + 0);          //  8 MB
    bf16*  wqkv = (bf16*)(ws + 8388608);    //  6 MB
    bf16*  wo   = (bf16*)(ws + 14680064);   //  2 MB
    bf16*  win  = (bf16*)(ws + 16777216);   //  8 MB
    bf16*  wout = (bf16*)(ws + 25165824);   //  8 MB
    bf16*  qkvb = (bf16*)(ws + 33554432);   // 24 MB (dead after attn)
    bf16*  vtb  = (bf16*)(ws + 58720256);   //  8 MB (dead after attn)
    bf16*  zbuf = (bf16*)(ws + 67633152);   //  8 MB
    bf16*  xmid = (bf16*)(ws + 76021760);   //  8 MB
    bf16*  hbuf = (bf16*)(ws + 84410368);   // 32 MB
    bf16*  partb = (bf16*)(ws + 33554432);  // 32 MB = 4 x 8 MB bf16 partials
                                            // (aliases qkvb+vtb, dead by MLP2)

    cvt_all<<<16384, 256, 0, stream>>>(x, WQ, WK, WV, WO, Win, Wout,
                                       xb, wqkv, wo, win, wout);

    // QKV: [4096x1024] x [3072x1024]^T (3 blocks/CU -> pipe)
    gemm_pipe<0><<<dim3(24, 32), 256, 0, stream>>>(xb, 1024, wqkv, 1024, 1024,
                                                   nullptr, qkvb, 3072, nullptr, nullptr);
    // attn pass 1 + fused V transpose (R15): produces vtb directly.
    attn_stats<<<dim3(16, 32), 512, 0, stream>>>(qkvb, vtb);
    attn_av<<<dim3(16, 32), 512, 0, stream>>>(qkvb, vtb, zbuf);
    // WO: z @ W_O^T + x (pipelined BK=64, XCD-chunked)
    gemm_pipe64<1><<<dim3(16, 32), 256, 0, stream>>>(zbuf, 1024, wo, 1024, 1024,
                                                     out, xmid, 1024, nullptr, x);
    // MLP1: relu(xmid @ W_in^T + b_in) — 256^2 4-phase deep-pipe, 1 block/CU
    gemm_deep<2><<<dim3(16, 16), 512, 0, stream>>>(xmid, 1024, win, 1024, 1024,
                                                   hbuf, 4096, bin);
    // MLP2: 256^2 4-phase deep-pipe, split-K=4 (256 blocks = 1/CU), bf16
    // partials into dead attn buffers, then fused reduce (+b_out).
    gemm_deep<0><<<dim3(16, 4, 4), 512, 0, stream>>>(hbuf, 4096, wout, 4096, 1024,
                                                     partb, 1024, nullptr);
    mlp2_reduce<<<4096, 256, 0, stream>>>(partb, bout, out);
}